// Round 1
// baseline (565.488 us; speedup 1.0000x reference)
//
#include <hip/hip_runtime.h>
#include <hip/hip_bf16.h>

typedef __bf16 bf16x8 __attribute__((ext_vector_type(8)));
typedef float f32x4 __attribute__((ext_vector_type(4)));

#define GLDS16(g, s)                                                         \
  __builtin_amdgcn_global_load_lds(                                          \
      (const __attribute__((address_space(1))) void*)(g),                    \
      (__attribute__((address_space(3))) void*)(s), 16, 0, 0)

__device__ __forceinline__ void store1(__hip_bfloat16* p, float v) { *p = __float2bfloat16(v); }
__device__ __forceinline__ void store1(float* p, float v) { *p = v; }

// ---------------- cast fp32 -> bf16 (4 elems/thread, vectorized) ----------------
__global__ __launch_bounds__(256) void cast_f32_to_bf16(const float4* __restrict__ in,
                                                        ushort4* __restrict__ out, int n4) {
  int i = blockIdx.x * 256 + threadIdx.x;
  if (i >= n4) return;
  float4 v = in[i];
  union { ushort4 u; __hip_bfloat16 h[4]; } o;
  o.h[0] = __float2bfloat16(v.x);
  o.h[1] = __float2bfloat16(v.y);
  o.h[2] = __float2bfloat16(v.z);
  o.h[3] = __float2bfloat16(v.w);
  out[i] = o.u;
}

// ---------------- bf16 GEMM: C(MxN) = A(MxK) * B(NxK)^T ----------------
// 128x128 tile, BK=32, 256 threads = 4 waves (2x2), 4x4 16x16x32 MFMA frags/wave.
template <typename OutT>
__global__ __launch_bounds__(256) void gemm_bt(const __hip_bfloat16* __restrict__ A,
                                               const __hip_bfloat16* __restrict__ B,
                                               OutT* __restrict__ C,
                                               int M, int N, int K) {
  __shared__ __hip_bfloat16 As[128 * 32];
  __shared__ __hip_bfloat16 Bs[128 * 32];
  const int t = threadIdx.x;
  const int w = t >> 6, l = t & 63;
  const int m0 = blockIdx.y * 128;
  const int n0 = blockIdx.x * 128;
  const int wm = (w >> 1) * 64, wn = (w & 1) * 64;

  // staging: chunk c = i*256 + t covers tile row c/4, 8-elem (16B) piece (c&3)*8
  const int r0 = t >> 2, e0 = (t & 3) * 8;
  const __hip_bfloat16* a0 = A + (size_t)(m0 + r0) * K + e0;
  const __hip_bfloat16* a1 = A + (size_t)(m0 + r0 + 64) * K + e0;
  const __hip_bfloat16* b0 = B + (size_t)(n0 + r0) * K + e0;
  const __hip_bfloat16* b1 = B + (size_t)(n0 + r0 + 64) * K + e0;

  f32x4 acc[4][4] = {};
  const int lr = l & 15;
  const int lkB = (l >> 4) * 16;  // byte offset of this lane's k-slot

  for (int k0 = 0; k0 < K; k0 += 32) {
    __syncthreads();  // previous compute done reading LDS
    GLDS16(a0 + k0, (char*)As + t * 16);
    GLDS16(a1 + k0, (char*)As + t * 16 + 4096);
    GLDS16(b0 + k0, (char*)Bs + t * 16);
    GLDS16(b1 + k0, (char*)Bs + t * 16 + 4096);
    __syncthreads();  // drains vmcnt -> tiles ready

    bf16x8 af[4], bfr[4];
#pragma unroll
    for (int mi = 0; mi < 4; ++mi)
      af[mi] = *(const bf16x8*)((const char*)As + (wm + mi * 16 + lr) * 64 + lkB);
#pragma unroll
    for (int ni = 0; ni < 4; ++ni)
      bfr[ni] = *(const bf16x8*)((const char*)Bs + (wn + ni * 16 + lr) * 64 + lkB);
#pragma unroll
    for (int mi = 0; mi < 4; ++mi)
#pragma unroll
      for (int ni = 0; ni < 4; ++ni)
        acc[mi][ni] = __builtin_amdgcn_mfma_f32_16x16x32_bf16(af[mi], bfr[ni], acc[mi][ni], 0, 0, 0);
  }

  // C/D layout (measured): col = l&15, row = (l>>4)*4 + i
  const int crow = (l >> 4) * 4, ccol = l & 15;
#pragma unroll
  for (int mi = 0; mi < 4; ++mi)
#pragma unroll
    for (int ni = 0; ni < 4; ++ni)
#pragma unroll
      for (int i = 0; i < 4; ++i) {
        size_t idx = (size_t)(m0 + wm + mi * 16 + crow + i) * N + (n0 + wn + ni * 16 + ccol);
        store1(&C[idx], acc[mi][ni][i]);
      }
}

// ---------------- flash attention (causal), bf16 in/out ----------------
// Q/K/V/O layout: (B*T, D) rows, head h at cols [h*128, h*128+128).
// Block: 4 waves x 16 q-rows = 64 q rows per (b,h). Key tiles of 64.
__global__ __launch_bounds__(256) void flash_attn(const __hip_bfloat16* __restrict__ Qg,
                                                  const __hip_bfloat16* __restrict__ Kg,
                                                  const __hip_bfloat16* __restrict__ Vg,
                                                  __hip_bfloat16* __restrict__ Og) {
  __shared__ __hip_bfloat16 Ks[64 * 128];
  __shared__ __hip_bfloat16 Vs[64 * 128];
  __shared__ __hip_bfloat16 Ps[4][16 * 64];

  const int bh = blockIdx.y;                 // 0..31
  const int b = bh >> 4, h = bh & 15;
  const int qt = (int)gridDim.x - 1 - blockIdx.x;  // heavy (late) q-tiles dispatch first
  const int q0 = qt * 64;
  const int t = threadIdx.x, w = t >> 6, l = t & 63;
  const int lr = l & 15;
  const int lk8 = (l >> 4) * 8;

  const size_t base = ((size_t)b * 2048) * 2048 + (size_t)h * 128;

  // Q fragments in registers: rows q0 + w*16 + lr, dims kk*32 + lk8 .. +8
  bf16x8 qf[4];
  {
    const __hip_bfloat16* qrow = Qg + base + (size_t)(q0 + w * 16 + lr) * 2048;
#pragma unroll
    for (int kk = 0; kk < 4; ++kk)
      qf[kk] = *(const bf16x8*)(qrow + kk * 32 + lk8);
  }

  f32x4 o_acc[8] = {};  // O[16 q][128 d]: 8 col-frags; lane: row=(l>>4)*4+i, col=nc*16+lr
  float m_run[4], l_run[4];
#pragma unroll
  for (int i = 0; i < 4; ++i) { m_run[i] = -1e30f; l_run[i] = 0.f; }

  const float scale = 0.08838834764831843f;  // 1/sqrt(128)
  const int nt = qt + 1;

  for (int kt = 0; kt < nt; ++kt) {
    const int kb = kt * 64;
    __syncthreads();  // all waves done reading previous K/V tiles
#pragma unroll
    for (int i = 0; i < 4; ++i) {
      int c = i * 256 + t;
      int kr = c >> 4, ke = (c & 15) * 8;
      GLDS16(Kg + base + (size_t)(kb + kr) * 2048 + ke, (char*)Ks + c * 16);
      GLDS16(Vg + base + (size_t)(kb + kr) * 2048 + ke, (char*)Vs + c * 16);
    }
    __syncthreads();  // tiles ready

    // S = Q * K^T for 4 key-blocks of 16
    f32x4 s[4];
#pragma unroll
    for (int nk = 0; nk < 4; ++nk) {
      f32x4 z = {};
      s[nk] = z;
#pragma unroll
      for (int kk = 0; kk < 4; ++kk) {
        bf16x8 kf = *(const bf16x8*)((const char*)Ks + (nk * 16 + lr) * 256 + kk * 64 + (l >> 4) * 16);
        s[nk] = __builtin_amdgcn_mfma_f32_16x16x32_bf16(qf[kk], kf, s[nk], 0, 0, 0);
      }
    }

    // scale + causal mask (only the diagonal tile needs it)
    const bool last = (kt == nt - 1);
#pragma unroll
    for (int nk = 0; nk < 4; ++nk)
#pragma unroll
      for (int i = 0; i < 4; ++i) {
        float v = s[nk][i] * scale;
        if (last) {
          int qi = q0 + w * 16 + (l >> 4) * 4 + i;
          int ki = kb + nk * 16 + lr;
          if (ki > qi) v = -1e30f;
        }
        s[nk][i] = v;
      }

    // online softmax; rows live at lanes sharing l>>4, cols across l&15
#pragma unroll
    for (int i = 0; i < 4; ++i) {
      float mx = fmaxf(fmaxf(s[0][i], s[1][i]), fmaxf(s[2][i], s[3][i]));
      mx = fmaxf(mx, __shfl_xor(mx, 1));
      mx = fmaxf(mx, __shfl_xor(mx, 2));
      mx = fmaxf(mx, __shfl_xor(mx, 4));
      mx = fmaxf(mx, __shfl_xor(mx, 8));
      float mnew = fmaxf(m_run[i], mx);
      float rs = __expf(m_run[i] - mnew);
      float sum = 0.f;
#pragma unroll
      for (int nk = 0; nk < 4; ++nk) {
        float p = __expf(s[nk][i] - mnew);
        s[nk][i] = p;
        sum += p;
      }
      sum += __shfl_xor(sum, 1);
      sum += __shfl_xor(sum, 2);
      sum += __shfl_xor(sum, 4);
      sum += __shfl_xor(sum, 8);
      l_run[i] = l_run[i] * rs + sum;
      m_run[i] = mnew;
#pragma unroll
      for (int nc = 0; nc < 8; ++nc) o_acc[nc][i] *= rs;
    }

    // P -> per-wave LDS (C-layout out, A-frag layout back in)
#pragma unroll
    for (int nk = 0; nk < 4; ++nk)
#pragma unroll
      for (int i = 0; i < 4; ++i)
        Ps[w][((l >> 4) * 4 + i) * 64 + nk * 16 + lr] = __float2bfloat16(s[nk][i]);

    // O += P * V
#pragma unroll
    for (int kk = 0; kk < 2; ++kk) {
      bf16x8 pf = *(const bf16x8*)(&Ps[w][lr * 64 + kk * 32 + lk8]);
#pragma unroll
      for (int nc = 0; nc < 8; ++nc) {
        bf16x8 vf;
#pragma unroll
        for (int j = 0; j < 8; ++j)
          vf[j] = *(const __bf16*)&Vs[(kk * 32 + lk8 + j) * 128 + nc * 16 + lr];
        o_acc[nc] = __builtin_amdgcn_mfma_f32_16x16x32_bf16(pf, vf, o_acc[nc], 0, 0, 0);
      }
    }
  }

  const int crow = (l >> 4) * 4;
#pragma unroll
  for (int nc = 0; nc < 8; ++nc)
#pragma unroll
    for (int i = 0; i < 4; ++i) {
      float val = o_acc[nc][i] / l_run[i];
      Og[base + (size_t)(q0 + w * 16 + crow + i) * 2048 + nc * 16 + lr] = __float2bfloat16(val);
    }
}

// ---------------- launch ----------------
extern "C" void kernel_launch(void* const* d_in, const int* in_sizes, int n_in,
                              void* d_out, int out_size, void* d_ws, size_t ws_size,
                              hipStream_t stream) {
  const float* x  = (const float*)d_in[0];
  const float* wq = (const float*)d_in[1];
  const float* wk = (const float*)d_in[2];
  const float* wv = (const float*)d_in[3];
  const float* wo = (const float*)d_in[4];
  float* out = (float*)d_out;

  const int BT = 4096, D = 2048;            // B*T, model dim
  const size_t ND = (size_t)D * D;          // 4M elems
  const size_t NX = (size_t)BT * D;         // 8M elems

  __hip_bfloat16* xb  = (__hip_bfloat16*)d_ws;
  __hip_bfloat16* wqb = xb + NX;
  __hip_bfloat16* wkb = wqb + ND;
  __hip_bfloat16* wvb = wkb + ND;
  __hip_bfloat16* wob = wvb + ND;
  __hip_bfloat16* Qb  = wob + ND;
  __hip_bfloat16* Kb  = Qb + NX;
  __hip_bfloat16* Vb  = Kb + NX;
  __hip_bfloat16* Ab  = Vb + NX;

  cast_f32_to_bf16<<<(int)(NX / 4 / 256), 256, 0, stream>>>((const float4*)x,  (ushort4*)xb,  (int)(NX / 4));
  cast_f32_to_bf16<<<(int)(ND / 4 / 256), 256, 0, stream>>>((const float4*)wq, (ushort4*)wqb, (int)(ND / 4));
  cast_f32_to_bf16<<<(int)(ND / 4 / 256), 256, 0, stream>>>((const float4*)wk, (ushort4*)wkb, (int)(ND / 4));
  cast_f32_to_bf16<<<(int)(ND / 4 / 256), 256, 0, stream>>>((const float4*)wv, (ushort4*)wvb, (int)(ND / 4));
  cast_f32_to_bf16<<<(int)(ND / 4 / 256), 256, 0, stream>>>((const float4*)wo, (ushort4*)wob, (int)(ND / 4));

  dim3 gg(D / 128, BT / 128);  // (16, 32)
  gemm_bt<__hip_bfloat16><<<gg, 256, 0, stream>>>(xb, wqb, Qb, BT, D, D);
  gemm_bt<__hip_bfloat16><<<gg, 256, 0, stream>>>(xb, wkb, Kb, BT, D, D);
  gemm_bt<__hip_bfloat16><<<gg, 256, 0, stream>>>(xb, wvb, Vb, BT, D, D);

  flash_attn<<<dim3(32, 32), 256, 0, stream>>>(Qb, Kb, Vb, Ab);

  gemm_bt<float><<<gg, 256, 0, stream>>>(Ab, wob, out, BT, D, D);
}

// Round 2
// 460.114 us; speedup vs baseline: 1.2290x; 1.2290x over previous
//
#include <hip/hip_runtime.h>
#include <hip/hip_bf16.h>

typedef __bf16 bf16x8 __attribute__((ext_vector_type(8)));
typedef float f32x4 __attribute__((ext_vector_type(4)));
typedef unsigned short u16x8 __attribute__((ext_vector_type(8)));

#define GLDS16(g, s)                                                         \
  __builtin_amdgcn_global_load_lds(                                          \
      (const __attribute__((address_space(1))) void*)(g),                    \
      (__attribute__((address_space(3))) void*)(s), 16, 0, 0)

__device__ __forceinline__ void store1(__hip_bfloat16* p, float v) { *p = __float2bfloat16(v); }
__device__ __forceinline__ void store1(float* p, float v) { *p = v; }

// ---------------- cast fp32 -> bf16 (4 elems/thread, vectorized) ----------------
__global__ __launch_bounds__(256) void cast_f32_to_bf16(const float4* __restrict__ in,
                                                        ushort4* __restrict__ out, int n4) {
  int i = blockIdx.x * 256 + threadIdx.x;
  if (i >= n4) return;
  float4 v = in[i];
  union { ushort4 u; __hip_bfloat16 h[4]; } o;
  o.h[0] = __float2bfloat16(v.x);
  o.h[1] = __float2bfloat16(v.y);
  o.h[2] = __float2bfloat16(v.z);
  o.h[3] = __float2bfloat16(v.w);
  out[i] = o.u;
}

// ---------------- bf16 GEMM: C(MxN) = A(MxK) * B(NxK)^T ----------------
// 128x128 tile, BK=32, 256 threads = 4 waves (2x2), 4x4 16x16x32 MFMA frags/wave.
template <typename OutT>
__global__ __launch_bounds__(256) void gemm_bt(const __hip_bfloat16* __restrict__ A,
                                               const __hip_bfloat16* __restrict__ B,
                                               OutT* __restrict__ C,
                                               int M, int N, int K) {
  __shared__ __hip_bfloat16 As[128 * 32];
  __shared__ __hip_bfloat16 Bs[128 * 32];
  const int t = threadIdx.x;
  const int w = t >> 6, l = t & 63;
  const int m0 = blockIdx.y * 128;
  const int n0 = blockIdx.x * 128;
  const int wm = (w >> 1) * 64, wn = (w & 1) * 64;

  const int r0 = t >> 2, e0 = (t & 3) * 8;
  const __hip_bfloat16* a0 = A + (size_t)(m0 + r0) * K + e0;
  const __hip_bfloat16* a1 = A + (size_t)(m0 + r0 + 64) * K + e0;
  const __hip_bfloat16* b0 = B + (size_t)(n0 + r0) * K + e0;
  const __hip_bfloat16* b1 = B + (size_t)(n0 + r0 + 64) * K + e0;

  f32x4 acc[4][4] = {};
  const int lr = l & 15;
  const int lkB = (l >> 4) * 16;

  for (int k0 = 0; k0 < K; k0 += 32) {
    __syncthreads();
    GLDS16(a0 + k0, (char*)As + t * 16);
    GLDS16(a1 + k0, (char*)As + t * 16 + 4096);
    GLDS16(b0 + k0, (char*)Bs + t * 16);
    GLDS16(b1 + k0, (char*)Bs + t * 16 + 4096);
    __syncthreads();

    bf16x8 af[4], bfr[4];
#pragma unroll
    for (int mi = 0; mi < 4; ++mi)
      af[mi] = *(const bf16x8*)((const char*)As + (wm + mi * 16 + lr) * 64 + lkB);
#pragma unroll
    for (int ni = 0; ni < 4; ++ni)
      bfr[ni] = *(const bf16x8*)((const char*)Bs + (wn + ni * 16 + lr) * 64 + lkB);
#pragma unroll
    for (int mi = 0; mi < 4; ++mi)
#pragma unroll
      for (int ni = 0; ni < 4; ++ni)
        acc[mi][ni] = __builtin_amdgcn_mfma_f32_16x16x32_bf16(af[mi], bfr[ni], acc[mi][ni], 0, 0, 0);
  }

  const int crow = (l >> 4) * 4, ccol = l & 15;
#pragma unroll
  for (int mi = 0; mi < 4; ++mi)
#pragma unroll
    for (int ni = 0; ni < 4; ++ni)
#pragma unroll
      for (int i = 0; i < 4; ++i) {
        size_t idx = (size_t)(m0 + wm + mi * 16 + crow + i) * N + (n0 + wn + ni * 16 + ccol);
        store1(&C[idx], acc[mi][ni][i]);
      }
}

// ---------------- flash attention (causal), bf16 in/out ----------------
// Q/K/V/O layout: (B*T, D) rows, head h at cols [h*128, h*128+128).
// Block: 4 waves x 16 q-rows = 64 q rows per (b,h). Key tiles of 64.
// LDS swizzles (T2): all tiles XOR their 16B-slot index with a row-derived
// 3-bit value so wave-wide b128 reads are bank-minimal (8 cycles).
__global__ __launch_bounds__(256) void flash_attn(const __hip_bfloat16* __restrict__ Qg,
                                                  const __hip_bfloat16* __restrict__ Kg,
                                                  const __hip_bfloat16* __restrict__ Vg,
                                                  __hip_bfloat16* __restrict__ Og) {
  __shared__ __hip_bfloat16 Ks[64 * 128];   // row-major [k][d], slot ^= (k&7)
  __shared__ __hip_bfloat16 Vt[128 * 64];   // transposed [d][k], slot ^= (d>>1)&7
  __shared__ __hip_bfloat16 Ps[4][16 * 64]; // per-wave [q][k], slot ^= (q&7)

  const int bh = blockIdx.y;                 // 0..31
  const int b = bh >> 4, h = bh & 15;
  const int qt = (int)gridDim.x - 1 - blockIdx.x;  // heavy (late) q-tiles dispatch first
  const int q0 = qt * 64;
  const int t = threadIdx.x, w = t >> 6, l = t & 63;
  const int lr = l & 15;
  const int hi = l >> 4;
  const int lk8 = hi * 8;

  const size_t base = ((size_t)b * 2048) * 2048 + (size_t)h * 128;

  // Q fragments in registers: rows q0 + w*16 + lr, dims kk*32 + lk8 .. +8
  bf16x8 qf[4];
  {
    const __hip_bfloat16* qrow = Qg + base + (size_t)(q0 + w * 16 + lr) * 2048;
#pragma unroll
    for (int kk = 0; kk < 4; ++kk)
      qf[kk] = *(const bf16x8*)(qrow + kk * 32 + lk8);
  }

  f32x4 o_acc[8] = {};  // O[16 q][128 d]: lane: row=(l>>4)*4+i, col=nc*16+lr
  float m_run[4], l_run[4];
#pragma unroll
  for (int i = 0; i < 4; ++i) { m_run[i] = -1e30f; l_run[i] = 0.f; }

  const float scale = 0.08838834764831843f;  // 1/sqrt(128)
  const int nt = qt + 1;

  for (int kt = 0; kt < nt; ++kt) {
    const int kb = kt * 64;
    __syncthreads();  // all waves done reading previous K/V tiles

    // K tile: global_load_lds, source slot pre-swizzled so LDS[k][slot^(k&7)] holds slot
#pragma unroll
    for (int i = 0; i < 4; ++i) {
      int c = i * 256 + t;
      int kr = c >> 4;
      int ke = ((c & 15) ^ (kr & 7)) * 8;
      GLDS16(Kg + base + (size_t)(kb + kr) * 2048 + ke, (char*)Ks + c * 16);
    }

    // V tile: reg-stage transposed. Unit u: k-pair kp, d-group dg (8 d).
    u16x8 vg0[2], vg1[2];
#pragma unroll
    for (int it = 0; it < 2; ++it) {
      int u = it * 256 + t;
      int kp = u >> 4, dg = u & 15;
      const unsigned short* vp =
          (const unsigned short*)(Vg + base + (size_t)(kb + kp * 2) * 2048 + dg * 8);
      vg0[it] = *(const u16x8*)vp;
      vg1[it] = *(const u16x8*)(vp + 2048);
    }
#pragma unroll
    for (int it = 0; it < 2; ++it) {
      int u = it * 256 + t;
      int kp = u >> 4, dg = u & 15;
#pragma unroll
      for (int j = 0; j < 8; ++j) {
        int d = dg * 8 + j;
        int off = d * 128 + ((((kp >> 2) ^ ((d >> 1) & 7)) << 4)) + (kp & 3) * 4;
        *(unsigned int*)((char*)Vt + off) =
            (unsigned int)vg0[it][j] | ((unsigned int)vg1[it][j] << 16);
      }
    }
    __syncthreads();  // tiles ready (drains vmcnt + lds writes)

    // S = Q * K^T for 4 key-blocks of 16
    f32x4 s[4];
#pragma unroll
    for (int nk = 0; nk < 4; ++nk) {
      f32x4 z = {};
      s[nk] = z;
#pragma unroll
      for (int kk = 0; kk < 4; ++kk) {
        int row = nk * 16 + lr;
        bf16x8 kf = *(const bf16x8*)((const char*)Ks + row * 256 +
                                     (((kk * 4 + hi) ^ (lr & 7)) << 4));
        s[nk] = __builtin_amdgcn_mfma_f32_16x16x32_bf16(qf[kk], kf, s[nk], 0, 0, 0);
      }
    }

    // scale + causal mask (only the diagonal tile needs it)
    const bool last = (kt == nt - 1);
#pragma unroll
    for (int nk = 0; nk < 4; ++nk)
#pragma unroll
      for (int i = 0; i < 4; ++i) {
        float v = s[nk][i] * scale;
        if (last) {
          int qi = q0 + w * 16 + hi * 4 + i;
          int ki = kb + nk * 16 + lr;
          if (ki > qi) v = -1e30f;
        }
        s[nk][i] = v;
      }

    // online softmax; rows live at lanes sharing l>>4, cols across l&15
#pragma unroll
    for (int i = 0; i < 4; ++i) {
      float mx = fmaxf(fmaxf(s[0][i], s[1][i]), fmaxf(s[2][i], s[3][i]));
      mx = fmaxf(mx, __shfl_xor(mx, 1));
      mx = fmaxf(mx, __shfl_xor(mx, 2));
      mx = fmaxf(mx, __shfl_xor(mx, 4));
      mx = fmaxf(mx, __shfl_xor(mx, 8));
      float mnew = fmaxf(m_run[i], mx);
      float rs = __expf(m_run[i] - mnew);
      float sum = 0.f;
#pragma unroll
      for (int nk = 0; nk < 4; ++nk) {
        float p = __expf(s[nk][i] - mnew);
        s[nk][i] = p;
        sum += p;
      }
      sum += __shfl_xor(sum, 1);
      sum += __shfl_xor(sum, 2);
      sum += __shfl_xor(sum, 4);
      sum += __shfl_xor(sum, 8);
      l_run[i] = l_run[i] * rs + sum;
      m_run[i] = mnew;
#pragma unroll
      for (int nc = 0; nc < 8; ++nc) o_acc[nc][i] *= rs;
    }

    // P -> per-wave LDS (C-layout out, A-frag layout back in), swizzled
#pragma unroll
    for (int nk = 0; nk < 4; ++nk)
#pragma unroll
      for (int i = 0; i < 4; ++i) {
        int row = hi * 4 + i;
        int col = nk * 16 + lr;
        int off = row * 128 + (((nk * 2 + (lr >> 3)) ^ (row & 7)) << 4) + (col & 7) * 2;
        *(__hip_bfloat16*)((char*)Ps[w] + off) = __float2bfloat16(s[nk][i]);
      }

    // O += P * V
#pragma unroll
    for (int kk = 0; kk < 2; ++kk) {
      bf16x8 pf = *(const bf16x8*)((const char*)Ps[w] + lr * 128 +
                                   (((kk * 4 + hi) ^ (lr & 7)) << 4));
#pragma unroll
      for (int nc = 0; nc < 8; ++nc) {
        int d = nc * 16 + lr;
        bf16x8 vfr = *(const bf16x8*)((const char*)Vt + d * 128 +
                                      (((kk * 4 + hi) ^ (lr >> 1)) << 4));
        o_acc[nc] = __builtin_amdgcn_mfma_f32_16x16x32_bf16(pf, vfr, o_acc[nc], 0, 0, 0);
      }
    }
  }

  const int crow = hi * 4;
#pragma unroll
  for (int nc = 0; nc < 8; ++nc)
#pragma unroll
    for (int i = 0; i < 4; ++i) {
      float val = o_acc[nc][i] / l_run[i];
      Og[base + (size_t)(q0 + w * 16 + crow + i) * 2048 + nc * 16 + lr] = __float2bfloat16(val);
    }
}

// ---------------- launch ----------------
extern "C" void kernel_launch(void* const* d_in, const int* in_sizes, int n_in,
                              void* d_out, int out_size, void* d_ws, size_t ws_size,
                              hipStream_t stream) {
  const float* x  = (const float*)d_in[0];
  const float* wq = (const float*)d_in[1];
  const float* wk = (const float*)d_in[2];
  const float* wv = (const float*)d_in[3];
  const float* wo = (const float*)d_in[4];
  float* out = (float*)d_out;

  const int BT = 4096, D = 2048;
  const size_t ND = (size_t)D * D;
  const size_t NX = (size_t)BT * D;

  __hip_bfloat16* xb  = (__hip_bfloat16*)d_ws;
  __hip_bfloat16* wqb = xb + NX;
  __hip_bfloat16* wkb = wqb + ND;
  __hip_bfloat16* wvb = wkb + ND;
  __hip_bfloat16* wob = wvb + ND;
  __hip_bfloat16* Qb  = wob + ND;
  __hip_bfloat16* Kb  = Qb + NX;
  __hip_bfloat16* Vb  = Kb + NX;
  __hip_bfloat16* Ab  = Vb + NX;

  cast_f32_to_bf16<<<(int)(NX / 4 / 256), 256, 0, stream>>>((const float4*)x,  (ushort4*)xb,  (int)(NX / 4));
  cast_f32_to_bf16<<<(int)(ND / 4 / 256), 256, 0, stream>>>((const float4*)wq, (ushort4*)wqb, (int)(ND / 4));
  cast_f32_to_bf16<<<(int)(ND / 4 / 256), 256, 0, stream>>>((const float4*)wk, (ushort4*)wkb, (int)(ND / 4));
  cast_f32_to_bf16<<<(int)(ND / 4 / 256), 256, 0, stream>>>((const float4*)wv, (ushort4*)wvb, (int)(ND / 4));
  cast_f32_to_bf16<<<(int)(ND / 4 / 256), 256, 0, stream>>>((const float4*)wo, (ushort4*)wob, (int)(ND / 4));

  dim3 gg(D / 128, BT / 128);  // (16, 32)
  gemm_bt<__hip_bfloat16><<<gg, 256, 0, stream>>>(xb, wqb, Qb, BT, D, D);
  gemm_bt<__hip_bfloat16><<<gg, 256, 0, stream>>>(xb, wkb, Kb, BT, D, D);
  gemm_bt<__hip_bfloat16><<<gg, 256, 0, stream>>>(xb, wvb, Vb, BT, D, D);

  flash_attn<<<dim3(32, 32), 256, 0, stream>>>(Qb, Kb, Vb, Ab);

  gemm_bt<float><<<gg, 256, 0, stream>>>(Ab, wob, out, BT, D, D);
}

// Round 3
// 407.268 us; speedup vs baseline: 1.3885x; 1.1298x over previous
//
#include <hip/hip_runtime.h>
#include <hip/hip_bf16.h>

typedef __bf16 bf16x8 __attribute__((ext_vector_type(8)));
typedef float f32x4 __attribute__((ext_vector_type(4)));
typedef unsigned short u16x8 __attribute__((ext_vector_type(8)));

#define GLDS16(g, s)                                                         \
  __builtin_amdgcn_global_load_lds(                                          \
      (const __attribute__((address_space(1))) void*)(g),                    \
      (__attribute__((address_space(3))) void*)(s), 16, 0, 0)

__device__ __forceinline__ void store1(__hip_bfloat16* p, float v) { *p = __float2bfloat16(v); }
__device__ __forceinline__ void store1(float* p, float v) { *p = v; }

// ---------------- cast fp32 -> bf16 ----------------
__global__ __launch_bounds__(256) void cast_f32_to_bf16(const float4* __restrict__ in,
                                                        ushort4* __restrict__ out, int n4) {
  int i = blockIdx.x * 256 + threadIdx.x;
  if (i >= n4) return;
  float4 v = in[i];
  union { ushort4 u; __hip_bfloat16 h[4]; } o;
  o.h[0] = __float2bfloat16(v.x);
  o.h[1] = __float2bfloat16(v.y);
  o.h[2] = __float2bfloat16(v.z);
  o.h[3] = __float2bfloat16(v.w);
  out[i] = o.u;
}

// ---------------- bf16 GEMM: C(MxN) = A(MxK) * B(NxK)^T (unchanged) ----------------
template <typename OutT>
__global__ __launch_bounds__(256) void gemm_bt(const __hip_bfloat16* __restrict__ A,
                                               const __hip_bfloat16* __restrict__ B,
                                               OutT* __restrict__ C,
                                               int M, int N, int K) {
  __shared__ __hip_bfloat16 As[128 * 32];
  __shared__ __hip_bfloat16 Bs[128 * 32];
  const int t = threadIdx.x;
  const int w = t >> 6, l = t & 63;
  const int m0 = blockIdx.y * 128;
  const int n0 = blockIdx.x * 128;
  const int wm = (w >> 1) * 64, wn = (w & 1) * 64;

  const int r0 = t >> 2, e0 = (t & 3) * 8;
  const __hip_bfloat16* a0 = A + (size_t)(m0 + r0) * K + e0;
  const __hip_bfloat16* a1 = A + (size_t)(m0 + r0 + 64) * K + e0;
  const __hip_bfloat16* b0 = B + (size_t)(n0 + r0) * K + e0;
  const __hip_bfloat16* b1 = B + (size_t)(n0 + r0 + 64) * K + e0;

  f32x4 acc[4][4] = {};
  const int lr = l & 15;
  const int lkB = (l >> 4) * 16;

  for (int k0 = 0; k0 < K; k0 += 32) {
    __syncthreads();
    GLDS16(a0 + k0, (char*)As + t * 16);
    GLDS16(a1 + k0, (char*)As + t * 16 + 4096);
    GLDS16(b0 + k0, (char*)Bs + t * 16);
    GLDS16(b1 + k0, (char*)Bs + t * 16 + 4096);
    __syncthreads();

    bf16x8 af[4], bfr[4];
#pragma unroll
    for (int mi = 0; mi < 4; ++mi)
      af[mi] = *(const bf16x8*)((const char*)As + (wm + mi * 16 + lr) * 64 + lkB);
#pragma unroll
    for (int ni = 0; ni < 4; ++ni)
      bfr[ni] = *(const bf16x8*)((const char*)Bs + (wn + ni * 16 + lr) * 64 + lkB);
#pragma unroll
    for (int mi = 0; mi < 4; ++mi)
#pragma unroll
      for (int ni = 0; ni < 4; ++ni)
        acc[mi][ni] = __builtin_amdgcn_mfma_f32_16x16x32_bf16(af[mi], bfr[ni], acc[mi][ni], 0, 0, 0);
  }

  const int crow = (l >> 4) * 4, ccol = l & 15;
#pragma unroll
  for (int mi = 0; mi < 4; ++mi)
#pragma unroll
    for (int ni = 0; ni < 4; ++ni)
#pragma unroll
      for (int i = 0; i < 4; ++i) {
        size_t idx = (size_t)(m0 + wm + mi * 16 + crow + i) * N + (n0 + wn + ni * 16 + ccol);
        store1(&C[idx], acc[mi][ni][i]);
      }
}

// ---------------- flash attention v3 (causal) ----------------
// QBLK=128 (4 waves x 32 q-rows), KVBLK=64. 512 blocks, balanced qt pairing.
// Pipelined: K via global_load_lds dbuf, V via reg-prefetch; raw barrier B keeps
// prefetch in flight across compute. LDS 64KB -> 2 blocks/CU.
__global__ __launch_bounds__(256, 2) void flash_attn(const __hip_bfloat16* __restrict__ Qg,
                                                     const __hip_bfloat16* __restrict__ Kg,
                                                     const __hip_bfloat16* __restrict__ Vg,
                                                     __hip_bfloat16* __restrict__ Og) {
  __shared__ __hip_bfloat16 Ks[2][64 * 128];  // [k][d], slot ^= (k&7) (via source pre-swizzle)
  __shared__ __hip_bfloat16 Vt[128 * 64];     // [d][k], slot ^= ((d>>3)^d)&7
  __shared__ __hip_bfloat16 Ps[4][32 * 64];   // per-wave [q][k], slot ^= (q&7)

  const int mblk = blockIdx.x;
  const int bh = mblk & 31;
  const int jj = mblk >> 5;                   // 0..15; heavy q-tiles dispatch first
  const int qt = (jj < 8) ? (15 - jj) : (jj - 8);  // pair (c, c+256) sums to 34 tiles
  const int b = bh >> 4, h = bh & 15;
  const int q0 = qt * 128;
  const int t = threadIdx.x, w = t >> 6, l = t & 63;
  const int lr = l & 15, hi = l >> 4;
  const size_t base = ((size_t)b * 2048) * 2048 + (size_t)h * 128;
  const int nt = 2 * qt + 2;
  const float scale = 0.08838834764831843f;  // 1/sqrt(128)

  // Q fragments: 2 row-groups of 16
  bf16x8 qf[2][4];
#pragma unroll
  for (int g = 0; g < 2; ++g) {
    const __hip_bfloat16* qrow = Qg + base + (size_t)(q0 + w * 32 + g * 16 + lr) * 2048;
#pragma unroll
    for (int kk = 0; kk < 4; ++kk)
      qf[g][kk] = *(const bf16x8*)(qrow + kk * 32 + hi * 8);
  }

  f32x4 o_acc[2][8] = {};
  float m_run[2][4], l_run[2][4];
#pragma unroll
  for (int g = 0; g < 2; ++g)
#pragma unroll
    for (int i = 0; i < 4; ++i) { m_run[g][i] = -1e30f; l_run[g][i] = 0.f; }

  // K staging: 4 chunks/thread, source slot pre-swizzled (k&7)
  const __hip_bfloat16* kptr[4];
#pragma unroll
  for (int i = 0; i < 4; ++i) {
    int c = i * 256 + t;
    int kr = c >> 4;
    int ke = ((c & 15) ^ (kr & 7)) * 8;
    kptr[i] = Kg + base + (size_t)kr * 2048 + ke;
  }
  // V staging: 2 units/thread, rows (kp*2, kp*2+1), cols lr*8..+7
  const __hip_bfloat16* vptr[2];
#pragma unroll
  for (int it = 0; it < 2; ++it) {
    int kp = it * 16 + w * 4 + hi;
    vptr[it] = Vg + base + (size_t)(kp * 2) * 2048 + lr * 8;
  }

  u16x8 va[2], vb[2];
  // prologue: prefetch tile 0
#pragma unroll
  for (int i = 0; i < 4; ++i)
    GLDS16(kptr[i], (char*)Ks[0] + (i * 256 + t) * 16);
#pragma unroll
  for (int it = 0; it < 2; ++it) {
    va[it] = *(const u16x8*)vptr[it];
    vb[it] = *(const u16x8*)(vptr[it] + 2048);
  }

  for (int kt = 0; kt < nt; ++kt) {
    const int cur = kt & 1;
    const int kb = kt * 64;
    __syncthreads();  // A: all waves done reading Vt/Ks[cur^1]; drains prefetch (in flight since prev compute)

    // write Vt transposed; write banks 2-way (free): slot = (it*4+w) ^ ((d>>3)^d)&7
#pragma unroll
    for (int it = 0; it < 2; ++it)
#pragma unroll
      for (int j2 = 0; j2 < 8; ++j2) {
        int d = lr * 8 + j2;
        int sw = (lr ^ j2) & 7;  // == ((d>>3)^d)&7
        int off = d * 128 + (((it * 4 + w) ^ sw) << 4) + hi * 4;
        *(unsigned int*)((char*)Vt + off) =
            (unsigned int)va[it][j2] | ((unsigned int)vb[it][j2] << 16);
      }
    // prefetch next tile (stays in flight through this tile's compute)
    if (kt + 1 < nt) {
      const size_t adv = (size_t)(kb + 64) * 2048;
#pragma unroll
      for (int i = 0; i < 4; ++i)
        GLDS16(kptr[i] + adv, (char*)Ks[cur ^ 1] + (i * 256 + t) * 16);
#pragma unroll
      for (int it = 0; it < 2; ++it) {
        va[it] = *(const u16x8*)(vptr[it] + adv);
        vb[it] = *(const u16x8*)(vptr[it] + adv + 2048);
      }
    }
    asm volatile("s_waitcnt lgkmcnt(0)" ::: "memory");  // Vt writes visible
    __builtin_amdgcn_s_barrier();  // B: raw (no vmcnt drain -> prefetch survives)

    if (!(kt == nt - 1 && w < 2)) {  // skip fully-masked waves (barriers already passed)
      const char* ks = (const char*)Ks[cur];
      // S = Q K^T
      f32x4 s[2][4];
#pragma unroll
      for (int g = 0; g < 2; ++g)
#pragma unroll
        for (int nk = 0; nk < 4; ++nk) { f32x4 z = {}; s[g][nk] = z; }
#pragma unroll
      for (int nk = 0; nk < 4; ++nk)
#pragma unroll
        for (int kk = 0; kk < 4; ++kk) {
          bf16x8 kf = *(const bf16x8*)(ks + (nk * 16 + lr) * 256 +
                                       (((kk * 4 + hi) ^ (lr & 7)) << 4));
#pragma unroll
          for (int g = 0; g < 2; ++g)
            s[g][nk] = __builtin_amdgcn_mfma_f32_16x16x32_bf16(qf[g][kk], kf, s[g][nk], 0, 0, 0);
        }

      // scale + causal mask (only last two tiles can touch the diagonal)
      const bool maskt = (kt >= nt - 2);
#pragma unroll
      for (int g = 0; g < 2; ++g)
#pragma unroll
        for (int nk = 0; nk < 4; ++nk)
#pragma unroll
          for (int i = 0; i < 4; ++i) {
            float v = s[g][nk][i] * scale;
            if (maskt) {
              int qi = q0 + w * 32 + g * 16 + hi * 4 + i;
              int ki = kb + nk * 16 + lr;
              if (ki > qi) v = -1e30f;
            }
            s[g][nk][i] = v;
          }

      // online softmax (rows: lanes sharing hi; cols across lr x nk)
#pragma unroll
      for (int g = 0; g < 2; ++g)
#pragma unroll
        for (int i = 0; i < 4; ++i) {
          float mx = fmaxf(fmaxf(s[g][0][i], s[g][1][i]), fmaxf(s[g][2][i], s[g][3][i]));
          mx = fmaxf(mx, __shfl_xor(mx, 1));
          mx = fmaxf(mx, __shfl_xor(mx, 2));
          mx = fmaxf(mx, __shfl_xor(mx, 4));
          mx = fmaxf(mx, __shfl_xor(mx, 8));
          float mnew = fmaxf(m_run[g][i], mx);
          float rs = __expf(m_run[g][i] - mnew);
          float sum = 0.f;
#pragma unroll
          for (int nk = 0; nk < 4; ++nk) {
            float p = __expf(s[g][nk][i] - mnew);
            s[g][nk][i] = p;
            sum += p;
          }
          sum += __shfl_xor(sum, 1);
          sum += __shfl_xor(sum, 2);
          sum += __shfl_xor(sum, 4);
          sum += __shfl_xor(sum, 8);
          l_run[g][i] = l_run[g][i] * rs + sum;
          m_run[g][i] = mnew;
#pragma unroll
          for (int nc = 0; nc < 8; ++nc) o_acc[g][nc][i] *= rs;
        }

      // P -> per-wave LDS (swizzled), back as A-frags
#pragma unroll
      for (int g = 0; g < 2; ++g)
#pragma unroll
        for (int nk = 0; nk < 4; ++nk)
#pragma unroll
          for (int i = 0; i < 4; ++i) {
            int row = g * 16 + hi * 4 + i;
            int off = row * 128 + (((nk * 2 + (lr >> 3)) ^ (row & 7)) << 4) + (lr & 7) * 2;
            *(__hip_bfloat16*)((char*)Ps[w] + off) = __float2bfloat16(s[g][nk][i]);
          }

      // O += P V
#pragma unroll
      for (int kk = 0; kk < 2; ++kk) {
        bf16x8 pf[2];
#pragma unroll
        for (int g = 0; g < 2; ++g) {
          int row = g * 16 + lr;
          pf[g] = *(const bf16x8*)((const char*)Ps[w] + row * 128 +
                                   (((kk * 4 + hi) ^ (lr & 7)) << 4));
        }
#pragma unroll
        for (int nc = 0; nc < 8; ++nc) {
          int d = nc * 16 + lr;
          int sw = ((d >> 3) ^ d) & 7;
          bf16x8 vfr = *(const bf16x8*)((const char*)Vt + d * 128 +
                                        (((kk * 4 + hi) ^ sw) << 4));
#pragma unroll
          for (int g = 0; g < 2; ++g)
            o_acc[g][nc] = __builtin_amdgcn_mfma_f32_16x16x32_bf16(pf[g], vfr, o_acc[g][nc], 0, 0, 0);
        }
      }
    }
  }

#pragma unroll
  for (int g = 0; g < 2; ++g)
#pragma unroll
    for (int nc = 0; nc < 8; ++nc)
#pragma unroll
      for (int i = 0; i < 4; ++i) {
        float val = o_acc[g][nc][i] / l_run[g][i];
        Og[base + (size_t)(q0 + w * 32 + g * 16 + hi * 4 + i) * 2048 + nc * 16 + lr] =
            __float2bfloat16(val);
      }
}

// ---------------- launch ----------------
extern "C" void kernel_launch(void* const* d_in, const int* in_sizes, int n_in,
                              void* d_out, int out_size, void* d_ws, size_t ws_size,
                              hipStream_t stream) {
  const float* x  = (const float*)d_in[0];
  const float* wq = (const float*)d_in[1];
  const float* wk = (const float*)d_in[2];
  const float* wv = (const float*)d_in[3];
  const float* wo = (const float*)d_in[4];
  float* out = (float*)d_out;

  const int BT = 4096, D = 2048;
  const size_t ND = (size_t)D * D;
  const size_t NX = (size_t)BT * D;

  __hip_bfloat16* xb  = (__hip_bfloat16*)d_ws;
  __hip_bfloat16* wqb = xb + NX;
  __hip_bfloat16* wkb = wqb + ND;
  __hip_bfloat16* wvb = wkb + ND;
  __hip_bfloat16* wob = wvb + ND;
  __hip_bfloat16* Qb  = wob + ND;
  __hip_bfloat16* Kb  = Qb + NX;
  __hip_bfloat16* Vb  = Kb + NX;
  __hip_bfloat16* Ab  = Vb + NX;

  cast_f32_to_bf16<<<(int)(NX / 4 / 256), 256, 0, stream>>>((const float4*)x,  (ushort4*)xb,  (int)(NX / 4));
  cast_f32_to_bf16<<<(int)(ND / 4 / 256), 256, 0, stream>>>((const float4*)wq, (ushort4*)wqb, (int)(ND / 4));
  cast_f32_to_bf16<<<(int)(ND / 4 / 256), 256, 0, stream>>>((const float4*)wk, (ushort4*)wkb, (int)(ND / 4));
  cast_f32_to_bf16<<<(int)(ND / 4 / 256), 256, 0, stream>>>((const float4*)wv, (ushort4*)wvb, (int)(ND / 4));
  cast_f32_to_bf16<<<(int)(ND / 4 / 256), 256, 0, stream>>>((const float4*)wo, (ushort4*)wob, (int)(ND / 4));

  dim3 gg(D / 128, BT / 128);  // (16, 32)
  gemm_bt<__hip_bfloat16><<<gg, 256, 0, stream>>>(xb, wqb, Qb, BT, D, D);
  gemm_bt<__hip_bfloat16><<<gg, 256, 0, stream>>>(xb, wkb, Kb, BT, D, D);
  gemm_bt<__hip_bfloat16><<<gg, 256, 0, stream>>>(xb, wvb, Vb, BT, D, D);

  flash_attn<<<512, 256, 0, stream>>>(Qb, Kb, Vb, Ab);

  gemm_bt<float><<<gg, 256, 0, stream>>>(Ab, wob, out, BT, D, D);
}

// Round 4
// 333.356 us; speedup vs baseline: 1.6963x; 1.2217x over previous
//
#include <hip/hip_runtime.h>
#include <hip/hip_bf16.h>

typedef __bf16 bf16x8 __attribute__((ext_vector_type(8)));
typedef float f32x4 __attribute__((ext_vector_type(4)));
typedef unsigned short u16x8 __attribute__((ext_vector_type(8)));

#define GLDS16(g, s)                                                         \
  __builtin_amdgcn_global_load_lds(                                          \
      (const __attribute__((address_space(1))) void*)(g),                    \
      (__attribute__((address_space(3))) void*)(s), 16, 0, 0)

__device__ __forceinline__ void store1(__hip_bfloat16* p, float v) { *p = __float2bfloat16(v); }
__device__ __forceinline__ void store1(float* p, float v) { *p = v; }

// ---------------- cast fp32 -> bf16 ----------------
__global__ __launch_bounds__(256) void cast_f32_to_bf16(const float4* __restrict__ in,
                                                        ushort4* __restrict__ out, int n4) {
  int i = blockIdx.x * 256 + threadIdx.x;
  if (i >= n4) return;
  float4 v = in[i];
  union { ushort4 u; __hip_bfloat16 h[4]; } o;
  o.h[0] = __float2bfloat16(v.x);
  o.h[1] = __float2bfloat16(v.y);
  o.h[2] = __float2bfloat16(v.z);
  o.h[3] = __float2bfloat16(v.w);
  out[i] = o.u;
}

// ---------------- bf16 GEMM: C(MxN) = A(MxK) * B(NxK)^T (unchanged) ----------------
template <typename OutT>
__global__ __launch_bounds__(256) void gemm_bt(const __hip_bfloat16* __restrict__ A,
                                               const __hip_bfloat16* __restrict__ B,
                                               OutT* __restrict__ C,
                                               int M, int N, int K) {
  __shared__ __hip_bfloat16 As[128 * 32];
  __shared__ __hip_bfloat16 Bs[128 * 32];
  const int t = threadIdx.x;
  const int w = t >> 6, l = t & 63;
  const int m0 = blockIdx.y * 128;
  const int n0 = blockIdx.x * 128;
  const int wm = (w >> 1) * 64, wn = (w & 1) * 64;

  const int r0 = t >> 2, e0 = (t & 3) * 8;
  const __hip_bfloat16* a0 = A + (size_t)(m0 + r0) * K + e0;
  const __hip_bfloat16* a1 = A + (size_t)(m0 + r0 + 64) * K + e0;
  const __hip_bfloat16* b0 = B + (size_t)(n0 + r0) * K + e0;
  const __hip_bfloat16* b1 = B + (size_t)(n0 + r0 + 64) * K + e0;

  f32x4 acc[4][4] = {};
  const int lr = l & 15;
  const int lkB = (l >> 4) * 16;

  for (int k0 = 0; k0 < K; k0 += 32) {
    __syncthreads();
    GLDS16(a0 + k0, (char*)As + t * 16);
    GLDS16(a1 + k0, (char*)As + t * 16 + 4096);
    GLDS16(b0 + k0, (char*)Bs + t * 16);
    GLDS16(b1 + k0, (char*)Bs + t * 16 + 4096);
    __syncthreads();

    bf16x8 af[4], bfr[4];
#pragma unroll
    for (int mi = 0; mi < 4; ++mi)
      af[mi] = *(const bf16x8*)((const char*)As + (wm + mi * 16 + lr) * 64 + lkB);
#pragma unroll
    for (int ni = 0; ni < 4; ++ni)
      bfr[ni] = *(const bf16x8*)((const char*)Bs + (wn + ni * 16 + lr) * 64 + lkB);
#pragma unroll
    for (int mi = 0; mi < 4; ++mi)
#pragma unroll
      for (int ni = 0; ni < 4; ++ni)
        acc[mi][ni] = __builtin_amdgcn_mfma_f32_16x16x32_bf16(af[mi], bfr[ni], acc[mi][ni], 0, 0, 0);
  }

  const int crow = (l >> 4) * 4, ccol = l & 15;
#pragma unroll
  for (int mi = 0; mi < 4; ++mi)
#pragma unroll
    for (int ni = 0; ni < 4; ++ni)
#pragma unroll
      for (int i = 0; i < 4; ++i) {
        size_t idx = (size_t)(m0 + wm + mi * 16 + crow + i) * N + (n0 + wn + ni * 16 + ccol);
        store1(&C[idx], acc[mi][ni][i]);
      }
}

// ---------------- flash attention v4 (causal), swapped QK^T ----------------
// QBLK=128 (4 waves x 32 q-rows), KVBLK=64, 512 balanced blocks.
// S^T = mfma(K,Q): lane holds q=l&15, keys nk*16+4*hi+i -> in-register softmax
// (tree + 2 shfl_xor), P -> PV A-frag via cvt_pk + 16 ds_bpermute (no LDS trip).
__global__ __launch_bounds__(256, 2) void flash_attn(const __hip_bfloat16* __restrict__ Qg,
                                                     const __hip_bfloat16* __restrict__ Kg,
                                                     const __hip_bfloat16* __restrict__ Vg,
                                                     __hip_bfloat16* __restrict__ Og) {
  __shared__ __hip_bfloat16 Ks[2][64 * 128];  // [k][d], slot ^= (k&7) via source pre-swizzle
  __shared__ __hip_bfloat16 Vt[128 * 64];     // [d][k], slot ^= ((d>>3)^d)&7

  const int mblk = blockIdx.x;
  const int bh = mblk & 31;
  const int jj = mblk >> 5;                        // heavy q-tiles dispatch first
  const int qt = (jj < 8) ? (15 - jj) : (jj - 8);  // pair (c, c+256) sums to 34 tiles
  const int b = bh >> 4, h = bh & 15;
  const int q0 = qt * 128;
  const int t = threadIdx.x, w = t >> 6, l = t & 63;
  const int lr = l & 15, hi = l >> 4;
  const size_t base = ((size_t)b * 2048) * 2048 + (size_t)h * 128;
  const int nt = 2 * qt + 2;
  const float scale = 0.08838834764831843f;  // 1/sqrt(128)

  // bpermute source-lane byte addresses
  const int hi2 = (hi & 1) * 2;
  const int addrA = (((hi2) << 4) | lr) << 2;      // hi_src = 2*(hi&1)
  const int addrB = (((hi2 + 1) << 4) | lr) << 2;  // hi_src = 2*(hi&1)+1
  int addr_o[4];
#pragma unroll
  for (int i = 0; i < 4; ++i) addr_o[i] = ((l & 48) | (hi * 4 + i)) << 2;
  const bool hiHigh = (hi >> 1) != 0;

  // Q fragments (B-operand now; same layout: q on l&15, dims (l>>4)*8+j)
  bf16x8 qf[2][4];
#pragma unroll
  for (int g = 0; g < 2; ++g) {
    const __hip_bfloat16* qrow = Qg + base + (size_t)(q0 + w * 32 + g * 16 + lr) * 2048;
#pragma unroll
    for (int kk = 0; kk < 4; ++kk)
      qf[g][kk] = *(const bf16x8*)(qrow + kk * 32 + hi * 8);
  }

  f32x4 o_acc[2][8] = {};              // row=q=4*hi+i, col=d=nc*16+lr
  float m_run[2] = {-1e30f, -1e30f};   // per lane: q = l&15 (per g)
  float l_run[2] = {0.f, 0.f};

  // K staging: 4 chunks/thread, source slot pre-swizzled (k&7)
  const __hip_bfloat16* kptr[4];
#pragma unroll
  for (int i = 0; i < 4; ++i) {
    int c = i * 256 + t;
    int kr = c >> 4;
    int ke = ((c & 15) ^ (kr & 7)) * 8;
    kptr[i] = Kg + base + (size_t)kr * 2048 + ke;
  }
  // V staging: 2 units/thread
  const __hip_bfloat16* vptr[2];
#pragma unroll
  for (int it = 0; it < 2; ++it) {
    int kp = it * 16 + w * 4 + hi;
    vptr[it] = Vg + base + (size_t)(kp * 2) * 2048 + lr * 8;
  }

  u16x8 va[2], vb[2];
  // prologue: prefetch tile 0
#pragma unroll
  for (int i = 0; i < 4; ++i)
    GLDS16(kptr[i], (char*)Ks[0] + (i * 256 + t) * 16);
#pragma unroll
  for (int it = 0; it < 2; ++it) {
    va[it] = *(const u16x8*)vptr[it];
    vb[it] = *(const u16x8*)(vptr[it] + 2048);
  }

  for (int kt = 0; kt < nt; ++kt) {
    const int cur = kt & 1;
    const int kb = kt * 64;
    __syncthreads();  // A: drains prefetch (in flight since prev compute) + Vt readers done

    // write Vt transposed (write banks 2-way = free)
#pragma unroll
    for (int it = 0; it < 2; ++it)
#pragma unroll
      for (int j2 = 0; j2 < 8; ++j2) {
        int d = lr * 8 + j2;
        int sw = (lr ^ j2) & 7;  // == ((d>>3)^d)&7
        int off = d * 128 + (((it * 4 + w) ^ sw) << 4) + hi * 4;
        *(unsigned int*)((char*)Vt + off) =
            (unsigned int)va[it][j2] | ((unsigned int)vb[it][j2] << 16);
      }
    // prefetch next tile (stays in flight through this tile's compute)
    if (kt + 1 < nt) {
      const size_t adv = (size_t)(kb + 64) * 2048;
#pragma unroll
      for (int i = 0; i < 4; ++i)
        GLDS16(kptr[i] + adv, (char*)Ks[cur ^ 1] + (i * 256 + t) * 16);
#pragma unroll
      for (int it = 0; it < 2; ++it) {
        va[it] = *(const u16x8*)(vptr[it] + adv);
        vb[it] = *(const u16x8*)(vptr[it] + adv + 2048);
      }
    }
    asm volatile("s_waitcnt lgkmcnt(0)" ::: "memory");  // Vt writes visible
    __builtin_amdgcn_s_barrier();  // B: raw (no vmcnt drain -> prefetch survives)

    if (!(kt == nt - 1 && w < 2)) {  // fully-masked waves skip compute
      const char* ks = (const char*)Ks[cur];

      // S^T = K Q^T : lane holds col q=lr, rows key = nk*16 + 4*hi + i
      f32x4 st[2][4];
#pragma unroll
      for (int g = 0; g < 2; ++g)
#pragma unroll
        for (int nk = 0; nk < 4; ++nk) { f32x4 z = {}; st[g][nk] = z; }
#pragma unroll
      for (int nk = 0; nk < 4; ++nk)
#pragma unroll
        for (int kk = 0; kk < 4; ++kk) {
          bf16x8 kf = *(const bf16x8*)(ks + (nk * 16 + lr) * 256 +
                                       (((kk * 4 + hi) ^ (lr & 7)) << 4));
#pragma unroll
          for (int g = 0; g < 2; ++g)
            st[g][nk] = __builtin_amdgcn_mfma_f32_16x16x32_bf16(kf, qf[g][kk], st[g][nk], 0, 0, 0);
        }

      // scale + causal mask
      const bool maskt = (kt >= nt - 2);
#pragma unroll
      for (int g = 0; g < 2; ++g)
#pragma unroll
        for (int nk = 0; nk < 4; ++nk)
#pragma unroll
          for (int i = 0; i < 4; ++i) {
            float v = st[g][nk][i] * scale;
            if (maskt) {
              int ki = kb + nk * 16 + hi * 4 + i;
              int qi = q0 + w * 32 + g * 16 + lr;
              if (ki > qi) v = -1e30f;
            }
            st[g][nk][i] = v;
          }

      bf16x8 paf[2][2];
#pragma unroll
      for (int g = 0; g < 2; ++g) {
        // in-lane max tree (16) + cross-hi (2 shfl)
        float t0 = fmaxf(fmaxf(st[g][0][0], st[g][0][1]), fmaxf(st[g][0][2], st[g][0][3]));
        float t1 = fmaxf(fmaxf(st[g][1][0], st[g][1][1]), fmaxf(st[g][1][2], st[g][1][3]));
        float t2 = fmaxf(fmaxf(st[g][2][0], st[g][2][1]), fmaxf(st[g][2][2], st[g][2][3]));
        float t3 = fmaxf(fmaxf(st[g][3][0], st[g][3][1]), fmaxf(st[g][3][2], st[g][3][3]));
        float mx = fmaxf(fmaxf(t0, t1), fmaxf(t2, t3));
        mx = fmaxf(mx, __shfl_xor(mx, 16));
        mx = fmaxf(mx, __shfl_xor(mx, 32));

        // defer-max (T13): rescale only when max grew by > 8
        if (!__all(mx - m_run[g] <= 8.0f)) {
          float mnew = fmaxf(m_run[g], mx);
          float rs = __expf(m_run[g] - mnew);
          m_run[g] = mnew;
          l_run[g] *= rs;
          int rsi = __float_as_int(rs);
#pragma unroll
          for (int i = 0; i < 4; ++i) {
            float rso = __int_as_float(__builtin_amdgcn_ds_bpermute(addr_o[i], rsi));
#pragma unroll
            for (int nc = 0; nc < 8; ++nc) o_acc[g][nc][i] *= rso;
          }
        }

        // P = exp(S - m)
#pragma unroll
        for (int nk = 0; nk < 4; ++nk)
#pragma unroll
          for (int i = 0; i < 4; ++i)
            st[g][nk][i] = __expf(st[g][nk][i] - m_run[g]);

        float s0 = (st[g][0][0] + st[g][0][1]) + (st[g][0][2] + st[g][0][3]);
        float s1 = (st[g][1][0] + st[g][1][1]) + (st[g][1][2] + st[g][1][3]);
        float s2 = (st[g][2][0] + st[g][2][1]) + (st[g][2][2] + st[g][2][3]);
        float s3 = (st[g][3][0] + st[g][3][1]) + (st[g][3][2] + st[g][3][3]);
        float sm = (s0 + s1) + (s2 + s3);
        sm += __shfl_xor(sm, 16);
        sm += __shfl_xor(sm, 32);
        l_run[g] += sm;

        // pack pairs to bf16: pk[nk][pp] = {keys nk*16+4hi+2pp (lo), +1 (hi)}
        unsigned pk[4][2];
#pragma unroll
        for (int nk = 0; nk < 4; ++nk) {
          asm("v_cvt_pk_bf16_f32 %0, %1, %2"
              : "=v"(pk[nk][0]) : "v"(st[g][nk][0]), "v"(st[g][nk][1]));
          asm("v_cvt_pk_bf16_f32 %0, %1, %2"
              : "=v"(pk[nk][1]) : "v"(st[g][nk][2]), "v"(st[g][nk][3]));
        }

        // redistribute to PV A-frag: af[kk] elem 32kk+8hi+2p',+1 =
        // pk[2kk+(hi>>1)][p'&1] @ lane (lr | hi_src<<4), hi_src=2(hi&1)+(p'>>1)
#pragma unroll
        for (int kk = 0; kk < 2; ++kk) {
          unsigned au[4];
#pragma unroll
          for (int p = 0; p < 4; ++p) {
            int ad = (p < 2) ? addrA : addrB;
            int v0 = __builtin_amdgcn_ds_bpermute(ad, (int)pk[2 * kk][p & 1]);
            int v1 = __builtin_amdgcn_ds_bpermute(ad, (int)pk[2 * kk + 1][p & 1]);
            au[p] = hiHigh ? (unsigned)v1 : (unsigned)v0;
          }
          union { unsigned u[4]; bf16x8 v; } cv;
          cv.u[0] = au[0]; cv.u[1] = au[1]; cv.u[2] = au[2]; cv.u[3] = au[3];
          paf[g][kk] = cv.v;
        }
      }

      // O += P V
#pragma unroll
      for (int kk = 0; kk < 2; ++kk)
#pragma unroll
        for (int nc = 0; nc < 8; ++nc) {
          int d = nc * 16 + lr;
          int sw = ((d >> 3) ^ d) & 7;
          bf16x8 vfr = *(const bf16x8*)((const char*)Vt + d * 128 +
                                        (((kk * 4 + hi) ^ sw) << 4));
#pragma unroll
          for (int g = 0; g < 2; ++g)
            o_acc[g][nc] = __builtin_amdgcn_mfma_f32_16x16x32_bf16(paf[g][kk], vfr, o_acc[g][nc], 0, 0, 0);
        }
    }
  }

  // epilogue: redistribute l_run to o-layout, divide, store
#pragma unroll
  for (int g = 0; g < 2; ++g) {
    float lo[4];
#pragma unroll
    for (int i = 0; i < 4; ++i)
      lo[i] = __int_as_float(__builtin_amdgcn_ds_bpermute(addr_o[i], __float_as_int(l_run[g])));
#pragma unroll
    for (int nc = 0; nc < 8; ++nc)
#pragma unroll
      for (int i = 0; i < 4; ++i) {
        float val = o_acc[g][nc][i] / lo[i];
        Og[base + (size_t)(q0 + w * 32 + g * 16 + hi * 4 + i) * 2048 + nc * 16 + lr] =
            __float2bfloat16(val);
      }
  }
}

// ---------------- launch ----------------
extern "C" void kernel_launch(void* const* d_in, const int* in_sizes, int n_in,
                              void* d_out, int out_size, void* d_ws, size_t ws_size,
                              hipStream_t stream) {
  const float* x  = (const float*)d_in[0];
  const float* wq = (const float*)d_in[1];
  const float* wk = (const float*)d_in[2];
  const float* wv = (const float*)d_in[3];
  const float* wo = (const float*)d_in[4];
  float* out = (float*)d_out;

  const int BT = 4096, D = 2048;
  const size_t ND = (size_t)D * D;
  const size_t NX = (size_t)BT * D;

  __hip_bfloat16* xb  = (__hip_bfloat16*)d_ws;
  __hip_bfloat16* wqb = xb + NX;
  __hip_bfloat16* wkb = wqb + ND;
  __hip_bfloat16* wvb = wkb + ND;
  __hip_bfloat16* wob = wvb + ND;
  __hip_bfloat16* Qb  = wob + ND;
  __hip_bfloat16* Kb  = Qb + NX;
  __hip_bfloat16* Vb  = Kb + NX;
  __hip_bfloat16* Ab  = Vb + NX;

  cast_f32_to_bf16<<<(int)(NX / 4 / 256), 256, 0, stream>>>((const float4*)x,  (ushort4*)xb,  (int)(NX / 4));
  cast_f32_to_bf16<<<(int)(ND / 4 / 256), 256, 0, stream>>>((const float4*)wq, (ushort4*)wqb, (int)(ND / 4));
  cast_f32_to_bf16<<<(int)(ND / 4 / 256), 256, 0, stream>>>((const float4*)wk, (ushort4*)wkb, (int)(ND / 4));
  cast_f32_to_bf16<<<(int)(ND / 4 / 256), 256, 0, stream>>>((const float4*)wv, (ushort4*)wvb, (int)(ND / 4));
  cast_f32_to_bf16<<<(int)(ND / 4 / 256), 256, 0, stream>>>((const float4*)wo, (ushort4*)wob, (int)(ND / 4));

  dim3 gg(D / 128, BT / 128);  // (16, 32)
  gemm_bt<__hip_bfloat16><<<gg, 256, 0, stream>>>(xb, wqb, Qb, BT, D, D);
  gemm_bt<__hip_bfloat16><<<gg, 256, 0, stream>>>(xb, wkb, Kb, BT, D, D);
  gemm_bt<__hip_bfloat16><<<gg, 256, 0, stream>>>(xb, wvb, Vb, BT, D, D);

  flash_attn<<<512, 256, 0, stream>>>(Qb, Kb, Vb, Ab);

  gemm_bt<float><<<gg, 256, 0, stream>>>(Ab, wob, out, BT, D, D);
}

// Round 5
// 302.447 us; speedup vs baseline: 1.8697x; 1.1022x over previous
//
#include <hip/hip_runtime.h>
#include <hip/hip_bf16.h>

typedef __bf16 bf16x8 __attribute__((ext_vector_type(8)));
typedef float f32x4 __attribute__((ext_vector_type(4)));
typedef unsigned short u16x8 __attribute__((ext_vector_type(8)));

#define GLDS16(g, s)                                                         \
  __builtin_amdgcn_global_load_lds(                                          \
      (const __attribute__((address_space(1))) void*)(g),                    \
      (__attribute__((address_space(3))) void*)(s), 16, 0, 0)

__device__ __forceinline__ void store1(__hip_bfloat16* p, float v) { *p = __float2bfloat16(v); }
__device__ __forceinline__ void store1(float* p, float v) { *p = v; }

// ---------------- cast fp32 -> bf16 ----------------
__global__ __launch_bounds__(256) void cast_f32_to_bf16(const float4* __restrict__ in,
                                                        ushort4* __restrict__ out, int n4) {
  int i = blockIdx.x * 256 + threadIdx.x;
  if (i >= n4) return;
  float4 v = in[i];
  union { ushort4 u; __hip_bfloat16 h[4]; } o;
  o.h[0] = __float2bfloat16(v.x);
  o.h[1] = __float2bfloat16(v.y);
  o.h[2] = __float2bfloat16(v.z);
  o.h[3] = __float2bfloat16(v.w);
  out[i] = o.u;
}

// ---------------- pipelined bf16 GEMM: C(MxN) = A(MxK) * B(NxK)^T ----------------
// 256x128 tile, BK=64, 512 threads = 8 waves (4M x 2N), per-wave 64x64 (acc 4x4).
// Triple-buffered LDS (144KB), 2-tile prefetch via global_load_lds, counted
// vmcnt(6) (never drains in-loop), raw s_barrier. T2 swizzle: slot ^= row&7 via
// pre-swizzled GLOBAL source (LDS dest linear), same XOR on ds_read.
// Optionally muxes 3 B/C pairs (fused QKV) by N-tile group.
template <typename OutT>
__global__ __launch_bounds__(512, 2) void gemm8p(const __hip_bfloat16* __restrict__ A,
                                                 const __hip_bfloat16* __restrict__ B0,
                                                 const __hip_bfloat16* __restrict__ B1,
                                                 const __hip_bfloat16* __restrict__ B2,
                                                 OutT* __restrict__ C0,
                                                 OutT* __restrict__ C1,
                                                 OutT* __restrict__ C2,
                                                 int nBx, int nBy, int ntPerMat,
                                                 int N, int K) {
  __shared__ __hip_bfloat16 As[3][256 * 64];  // 32 KB each
  __shared__ __hip_bfloat16 Bs[3][128 * 64];  // 16 KB each

  const int t = threadIdx.x;
  const int w = t >> 6, l = t & 63;
  const int lr = l & 15, hi = l >> 4;

  // XCD-bijective swizzle (nwg % 8 == 0 for both launches)
  const int nwg = nBx * nBy;
  int id = (int)blockIdx.x;
  id = (id & 7) * (nwg >> 3) + (id >> 3);
  const int bx = id % nBx;
  const int by = id / nBx;

  const int sel = bx / ntPerMat;
  const __hip_bfloat16* Bm = (sel == 0) ? B0 : ((sel == 1) ? B1 : B2);
  OutT* Cm = (sel == 0) ? C0 : ((sel == 1) ? C1 : C2);
  const int n0 = (bx - sel * ntPerMat) * 128;
  const int m0 = by * 256;

  // staging: chunk c -> LDS row c>>3, 16B slot c&7; global col pre-swizzled
  const __hip_bfloat16* aptr[4];
#pragma unroll
  for (int i = 0; i < 4; ++i) {
    int c = i * 512 + t;
    int row = c >> 3;
    int slot = (c & 7) ^ (row & 7);
    aptr[i] = A + (size_t)(m0 + row) * K + slot * 8;
  }
  const __hip_bfloat16* bptr[2];
#pragma unroll
  for (int i = 0; i < 2; ++i) {
    int c = i * 512 + t;
    int row = c >> 3;
    int slot = (c & 7) ^ (row & 7);
    bptr[i] = Bm + (size_t)(n0 + row) * K + slot * 8;
  }

#define STAGE_G(buf, tt)                                                     \
  do {                                                                       \
    const size_t koff = (size_t)(tt) * 64;                                   \
    GLDS16(aptr[0] + koff, (char*)As[buf] + t * 16);                         \
    GLDS16(aptr[1] + koff, (char*)As[buf] + t * 16 + 8192);                  \
    GLDS16(aptr[2] + koff, (char*)As[buf] + t * 16 + 16384);                 \
    GLDS16(aptr[3] + koff, (char*)As[buf] + t * 16 + 24576);                 \
    GLDS16(bptr[0] + koff, (char*)Bs[buf] + t * 16);                         \
    GLDS16(bptr[1] + koff, (char*)Bs[buf] + t * 16 + 8192);                  \
  } while (0)

  const int wm = (w >> 1) * 64, wn = (w & 1) * 64;
  f32x4 acc[4][4] = {};
  const int NT = K / 64;
  const int sw = lr & 7;  // row&7 for all frag rows (row = base16*x + lr)

  // prologue: tiles 0,1 in flight; wait tile 0 (6 newest = tile 1 stay out)
  STAGE_G(0, 0);
  STAGE_G(1, 1);
  asm volatile("s_waitcnt vmcnt(6)" ::: "memory");
  __builtin_amdgcn_s_barrier();

  for (int tt = 0; tt < NT; ++tt) {
    const int buf = tt % 3;
    if (tt) {
      if (tt + 1 < NT)
        asm volatile("s_waitcnt vmcnt(6)" ::: "memory");
      else
        asm volatile("s_waitcnt vmcnt(0)" ::: "memory");
      __builtin_amdgcn_s_barrier();
    }
    if (tt + 2 < NT) STAGE_G((tt + 2) % 3, tt + 2);

    const char* as_ = (const char*)As[buf];
    const char* bs_ = (const char*)Bs[buf];

    bf16x8 bfr[4][2];
#pragma unroll
    for (int ni = 0; ni < 4; ++ni)
#pragma unroll
      for (int kk = 0; kk < 2; ++kk)
        bfr[ni][kk] = *(const bf16x8*)(bs_ + (wn + ni * 16 + lr) * 128 +
                                       (((kk * 4 + hi) ^ sw) << 4));
#pragma unroll
    for (int mi = 0; mi < 4; ++mi) {
      const char* arow = as_ + (wm + mi * 16 + lr) * 128;
      bf16x8 a0 = *(const bf16x8*)(arow + ((hi ^ sw) << 4));
      bf16x8 a1 = *(const bf16x8*)(arow + (((4 + hi) ^ sw) << 4));
      __builtin_amdgcn_s_setprio(1);
#pragma unroll
      for (int ni = 0; ni < 4; ++ni) {
        acc[mi][ni] = __builtin_amdgcn_mfma_f32_16x16x32_bf16(a0, bfr[ni][0], acc[mi][ni], 0, 0, 0);
        acc[mi][ni] = __builtin_amdgcn_mfma_f32_16x16x32_bf16(a1, bfr[ni][1], acc[mi][ni], 0, 0, 0);
      }
      __builtin_amdgcn_s_setprio(0);
    }
  }
#undef STAGE_G

  // C/D layout: col = lr, row = hi*4 + i
#pragma unroll
  for (int mi = 0; mi < 4; ++mi)
#pragma unroll
    for (int ni = 0; ni < 4; ++ni)
#pragma unroll
      for (int i = 0; i < 4; ++i) {
        size_t idx = (size_t)(m0 + wm + mi * 16 + hi * 4 + i) * N + (n0 + wn + ni * 16 + lr);
        store1(&Cm[idx], acc[mi][ni][i]);
      }
}

// ---------------- flash attention v4 (causal), swapped QK^T (unchanged) ----------------
__global__ __launch_bounds__(256, 2) void flash_attn(const __hip_bfloat16* __restrict__ Qg,
                                                     const __hip_bfloat16* __restrict__ Kg,
                                                     const __hip_bfloat16* __restrict__ Vg,
                                                     __hip_bfloat16* __restrict__ Og) {
  __shared__ __hip_bfloat16 Ks[2][64 * 128];  // [k][d], slot ^= (k&7) via source pre-swizzle
  __shared__ __hip_bfloat16 Vt[128 * 64];     // [d][k], slot ^= ((d>>3)^d)&7

  const int mblk = blockIdx.x;
  const int bh = mblk & 31;
  const int jj = mblk >> 5;                        // heavy q-tiles dispatch first
  const int qt = (jj < 8) ? (15 - jj) : (jj - 8);  // pair (c, c+256) sums to 34 tiles
  const int b = bh >> 4, h = bh & 15;
  const int q0 = qt * 128;
  const int t = threadIdx.x, w = t >> 6, l = t & 63;
  const int lr = l & 15, hi = l >> 4;
  const size_t base = ((size_t)b * 2048) * 2048 + (size_t)h * 128;
  const int nt = 2 * qt + 2;
  const float scale = 0.08838834764831843f;  // 1/sqrt(128)

  const int hi2 = (hi & 1) * 2;
  const int addrA = (((hi2) << 4) | lr) << 2;
  const int addrB = (((hi2 + 1) << 4) | lr) << 2;
  int addr_o[4];
#pragma unroll
  for (int i = 0; i < 4; ++i) addr_o[i] = ((l & 48) | (hi * 4 + i)) << 2;
  const bool hiHigh = (hi >> 1) != 0;

  bf16x8 qf[2][4];
#pragma unroll
  for (int g = 0; g < 2; ++g) {
    const __hip_bfloat16* qrow = Qg + base + (size_t)(q0 + w * 32 + g * 16 + lr) * 2048;
#pragma unroll
    for (int kk = 0; kk < 4; ++kk)
      qf[g][kk] = *(const bf16x8*)(qrow + kk * 32 + hi * 8);
  }

  f32x4 o_acc[2][8] = {};
  float m_run[2] = {-1e30f, -1e30f};
  float l_run[2] = {0.f, 0.f};

  const __hip_bfloat16* kptr[4];
#pragma unroll
  for (int i = 0; i < 4; ++i) {
    int c = i * 256 + t;
    int kr = c >> 4;
    int ke = ((c & 15) ^ (kr & 7)) * 8;
    kptr[i] = Kg + base + (size_t)kr * 2048 + ke;
  }
  const __hip_bfloat16* vptr[2];
#pragma unroll
  for (int it = 0; it < 2; ++it) {
    int kp = it * 16 + w * 4 + hi;
    vptr[it] = Vg + base + (size_t)(kp * 2) * 2048 + lr * 8;
  }

  u16x8 va[2], vb[2];
#pragma unroll
  for (int i = 0; i < 4; ++i)
    GLDS16(kptr[i], (char*)Ks[0] + (i * 256 + t) * 16);
#pragma unroll
  for (int it = 0; it < 2; ++it) {
    va[it] = *(const u16x8*)vptr[it];
    vb[it] = *(const u16x8*)(vptr[it] + 2048);
  }

  for (int kt = 0; kt < nt; ++kt) {
    const int cur = kt & 1;
    const int kb = kt * 64;
    __syncthreads();

#pragma unroll
    for (int it = 0; it < 2; ++it)
#pragma unroll
      for (int j2 = 0; j2 < 8; ++j2) {
        int d = lr * 8 + j2;
        int sw = (lr ^ j2) & 7;
        int off = d * 128 + (((it * 4 + w) ^ sw) << 4) + hi * 4;
        *(unsigned int*)((char*)Vt + off) =
            (unsigned int)va[it][j2] | ((unsigned int)vb[it][j2] << 16);
      }
    if (kt + 1 < nt) {
      const size_t adv = (size_t)(kb + 64) * 2048;
#pragma unroll
      for (int i = 0; i < 4; ++i)
        GLDS16(kptr[i] + adv, (char*)Ks[cur ^ 1] + (i * 256 + t) * 16);
#pragma unroll
      for (int it = 0; it < 2; ++it) {
        va[it] = *(const u16x8*)(vptr[it] + adv);
        vb[it] = *(const u16x8*)(vptr[it] + adv + 2048);
      }
    }
    asm volatile("s_waitcnt lgkmcnt(0)" ::: "memory");
    __builtin_amdgcn_s_barrier();

    if (!(kt == nt - 1 && w < 2)) {
      const char* ks = (const char*)Ks[cur];

      f32x4 st[2][4];
#pragma unroll
      for (int g = 0; g < 2; ++g)
#pragma unroll
        for (int nk = 0; nk < 4; ++nk) { f32x4 z = {}; st[g][nk] = z; }
#pragma unroll
      for (int nk = 0; nk < 4; ++nk)
#pragma unroll
        for (int kk = 0; kk < 4; ++kk) {
          bf16x8 kf = *(const bf16x8*)(ks + (nk * 16 + lr) * 256 +
                                       (((kk * 4 + hi) ^ (lr & 7)) << 4));
#pragma unroll
          for (int g = 0; g < 2; ++g)
            st[g][nk] = __builtin_amdgcn_mfma_f32_16x16x32_bf16(kf, qf[g][kk], st[g][nk], 0, 0, 0);
        }

      const bool maskt = (kt >= nt - 2);
#pragma unroll
      for (int g = 0; g < 2; ++g)
#pragma unroll
        for (int nk = 0; nk < 4; ++nk)
#pragma unroll
          for (int i = 0; i < 4; ++i) {
            float v = st[g][nk][i] * scale;
            if (maskt) {
              int ki = kb + nk * 16 + hi * 4 + i;
              int qi = q0 + w * 32 + g * 16 + lr;
              if (ki > qi) v = -1e30f;
            }
            st[g][nk][i] = v;
          }

      bf16x8 paf[2][2];
#pragma unroll
      for (int g = 0; g < 2; ++g) {
        float t0 = fmaxf(fmaxf(st[g][0][0], st[g][0][1]), fmaxf(st[g][0][2], st[g][0][3]));
        float t1 = fmaxf(fmaxf(st[g][1][0], st[g][1][1]), fmaxf(st[g][1][2], st[g][1][3]));
        float t2 = fmaxf(fmaxf(st[g][2][0], st[g][2][1]), fmaxf(st[g][2][2], st[g][2][3]));
        float t3 = fmaxf(fmaxf(st[g][3][0], st[g][3][1]), fmaxf(st[g][3][2], st[g][3][3]));
        float mx = fmaxf(fmaxf(t0, t1), fmaxf(t2, t3));
        mx = fmaxf(mx, __shfl_xor(mx, 16));
        mx = fmaxf(mx, __shfl_xor(mx, 32));

        if (!__all(mx - m_run[g] <= 8.0f)) {
          float mnew = fmaxf(m_run[g], mx);
          float rs = __expf(m_run[g] - mnew);
          m_run[g] = mnew;
          l_run[g] *= rs;
          int rsi = __float_as_int(rs);
#pragma unroll
          for (int i = 0; i < 4; ++i) {
            float rso = __int_as_float(__builtin_amdgcn_ds_bpermute(addr_o[i], rsi));
#pragma unroll
            for (int nc = 0; nc < 8; ++nc) o_acc[g][nc][i] *= rso;
          }
        }

#pragma unroll
        for (int nk = 0; nk < 4; ++nk)
#pragma unroll
          for (int i = 0; i < 4; ++i)
            st[g][nk][i] = __expf(st[g][nk][i] - m_run[g]);

        float s0 = (st[g][0][0] + st[g][0][1]) + (st[g][0][2] + st[g][0][3]);
        float s1 = (st[g][1][0] + st[g][1][1]) + (st[g][1][2] + st[g][1][3]);
        float s2 = (st[g][2][0] + st[g][2][1]) + (st[g][2][2] + st[g][2][3]);
        float s3 = (st[g][3][0] + st[g][3][1]) + (st[g][3][2] + st[g][3][3]);
        float sm = (s0 + s1) + (s2 + s3);
        sm += __shfl_xor(sm, 16);
        sm += __shfl_xor(sm, 32);
        l_run[g] += sm;

        unsigned pk[4][2];
#pragma unroll
        for (int nk = 0; nk < 4; ++nk) {
          asm("v_cvt_pk_bf16_f32 %0, %1, %2"
              : "=v"(pk[nk][0]) : "v"(st[g][nk][0]), "v"(st[g][nk][1]));
          asm("v_cvt_pk_bf16_f32 %0, %1, %2"
              : "=v"(pk[nk][1]) : "v"(st[g][nk][2]), "v"(st[g][nk][3]));
        }

#pragma unroll
        for (int kk = 0; kk < 2; ++kk) {
          unsigned au[4];
#pragma unroll
          for (int p = 0; p < 4; ++p) {
            int ad = (p < 2) ? addrA : addrB;
            int v0 = __builtin_amdgcn_ds_bpermute(ad, (int)pk[2 * kk][p & 1]);
            int v1 = __builtin_amdgcn_ds_bpermute(ad, (int)pk[2 * kk + 1][p & 1]);
            au[p] = hiHigh ? (unsigned)v1 : (unsigned)v0;
          }
          union { unsigned u[4]; bf16x8 v; } cv;
          cv.u[0] = au[0]; cv.u[1] = au[1]; cv.u[2] = au[2]; cv.u[3] = au[3];
          paf[g][kk] = cv.v;
        }
      }

#pragma unroll
      for (int kk = 0; kk < 2; ++kk)
#pragma unroll
        for (int nc = 0; nc < 8; ++nc) {
          int d = nc * 16 + lr;
          int sw = ((d >> 3) ^ d) & 7;
          bf16x8 vfr = *(const bf16x8*)((const char*)Vt + d * 128 +
                                        (((kk * 4 + hi) ^ sw) << 4));
#pragma unroll
          for (int g = 0; g < 2; ++g)
            o_acc[g][nc] = __builtin_amdgcn_mfma_f32_16x16x32_bf16(paf[g][kk], vfr, o_acc[g][nc], 0, 0, 0);
        }
    }
  }

#pragma unroll
  for (int g = 0; g < 2; ++g) {
    float lo[4];
#pragma unroll
    for (int i = 0; i < 4; ++i)
      lo[i] = __int_as_float(__builtin_amdgcn_ds_bpermute(addr_o[i], __float_as_int(l_run[g])));
#pragma unroll
    for (int nc = 0; nc < 8; ++nc)
#pragma unroll
      for (int i = 0; i < 4; ++i) {
        float val = o_acc[g][nc][i] / lo[i];
        Og[base + (size_t)(q0 + w * 32 + g * 16 + hi * 4 + i) * 2048 + nc * 16 + lr] =
            __float2bfloat16(val);
      }
  }
}

// ---------------- launch ----------------
extern "C" void kernel_launch(void* const* d_in, const int* in_sizes, int n_in,
                              void* d_out, int out_size, void* d_ws, size_t ws_size,
                              hipStream_t stream) {
  const float* x  = (const float*)d_in[0];
  const float* wq = (const float*)d_in[1];
  const float* wk = (const float*)d_in[2];
  const float* wv = (const float*)d_in[3];
  const float* wo = (const float*)d_in[4];
  float* out = (float*)d_out;

  const int BT = 4096, D = 2048;
  const size_t ND = (size_t)D * D;
  const size_t NX = (size_t)BT * D;

  __hip_bfloat16* xb  = (__hip_bfloat16*)d_ws;
  __hip_bfloat16* wqb = xb + NX;
  __hip_bfloat16* wkb = wqb + ND;
  __hip_bfloat16* wvb = wkb + ND;
  __hip_bfloat16* wob = wvb + ND;
  __hip_bfloat16* Qb  = wob + ND;
  __hip_bfloat16* Kb  = Qb + NX;
  __hip_bfloat16* Vb  = Kb + NX;
  __hip_bfloat16* Ab  = Vb + NX;

  cast_f32_to_bf16<<<(int)(NX / 4 / 256), 256, 0, stream>>>((const float4*)x,  (ushort4*)xb,  (int)(NX / 4));
  cast_f32_to_bf16<<<(int)(ND / 4 / 256), 256, 0, stream>>>((const float4*)wq, (ushort4*)wqb, (int)(ND / 4));
  cast_f32_to_bf16<<<(int)(ND / 4 / 256), 256, 0, stream>>>((const float4*)wk, (ushort4*)wkb, (int)(ND / 4));
  cast_f32_to_bf16<<<(int)(ND / 4 / 256), 256, 0, stream>>>((const float4*)wv, (ushort4*)wvb, (int)(ND / 4));
  cast_f32_to_bf16<<<(int)(ND / 4 / 256), 256, 0, stream>>>((const float4*)wo, (ushort4*)wob, (int)(ND / 4));

  // fused QKV: 16 M-tiles x 48 N-tiles (16 per matrix) = 768 blocks (3/CU)
  gemm8p<__hip_bfloat16><<<768, 512, 0, stream>>>(xb, wqb, wkb, wvb, Qb, Kb, Vb,
                                                  48, 16, 16, D, D);

  flash_attn<<<512, 256, 0, stream>>>(Qb, Kb, Vb, Ab);

  // output projection: 16 x 16 = 256 blocks (1/CU)
  gemm8p<float><<<256, 512, 0, stream>>>(Ab, wob, wob, wob, out, out, out,
                                         16, 16, 16, D, D);
}

// Round 6
// 302.016 us; speedup vs baseline: 1.8724x; 1.0014x over previous
//
#include <hip/hip_runtime.h>
#include <hip/hip_bf16.h>

typedef __bf16 bf16x8 __attribute__((ext_vector_type(8)));
typedef float f32x4 __attribute__((ext_vector_type(4)));
typedef unsigned short u16x8 __attribute__((ext_vector_type(8)));

#define GLDS16(g, s)                                                         \
  __builtin_amdgcn_global_load_lds(                                          \
      (const __attribute__((address_space(1))) void*)(g),                    \
      (__attribute__((address_space(3))) void*)(s), 16, 0, 0)

__device__ __forceinline__ void store1(__hip_bfloat16* p, float v) { *p = __float2bfloat16(v); }
__device__ __forceinline__ void store1(float* p, float v) { *p = v; }

// ---------------- cast fp32 -> bf16 ----------------
__global__ __launch_bounds__(256) void cast_f32_to_bf16(const float4* __restrict__ in,
                                                        ushort4* __restrict__ out, int n4) {
  int i = blockIdx.x * 256 + threadIdx.x;
  if (i >= n4) return;
  float4 v = in[i];
  union { ushort4 u; __hip_bfloat16 h[4]; } o;
  o.h[0] = __float2bfloat16(v.x);
  o.h[1] = __float2bfloat16(v.y);
  o.h[2] = __float2bfloat16(v.z);
  o.h[3] = __float2bfloat16(v.w);
  out[i] = o.u;
}

// ---------------- 8-phase 256x256 bf16 GEMM: C(MxN) = A(MxK) * B(NxK)^T --------------
// BK=64, 512 threads = 8 waves. Per phase all waves compute one 128x128 C-quadrant
// (per-wave 64x32 slice, 16 MFMA, 12 ds_read_b128). Half-tile staging S0=A0,S1=B0,
// S2=A1,S3=B1 (2 gloads/thread each); phase p of tile t issues S_p(t+1) into buf^1.
// Counted vmcnt(4) + one raw s_barrier per phase; never drains in the main loop.
// Schedule proof: entering P0 outstanding={S0..S3(t+1)}=8 -> wait 4 lands S0,S1 (=P0's
// needs); P1: +S0(t+2)=6 -> lands S2; P2: +S1'=6 -> lands S3; P3: needs already landed.
// Deposits always target the buffer not read this tile; barrier bounds skew to 1 phase.
template <typename OutT>
__global__ __launch_bounds__(512, 2) void gemm256(const __hip_bfloat16* __restrict__ A,
                                                  const __hip_bfloat16* __restrict__ B0,
                                                  const __hip_bfloat16* __restrict__ B1,
                                                  const __hip_bfloat16* __restrict__ B2,
                                                  OutT* __restrict__ C0,
                                                  OutT* __restrict__ C1,
                                                  OutT* __restrict__ C2,
                                                  int nBx, int nBy, int ntPerMat,
                                                  int N, int K) {
  __shared__ __hip_bfloat16 As[2][256 * 64];  // 32 KB per buf
  __shared__ __hip_bfloat16 Bs[2][256 * 64];  // 32 KB per buf

  const int t = threadIdx.x;
  const int w = t >> 6, l = t & 63;
  const int lr = l & 15, hi = l >> 4;

  // XCD-bijective swizzle (nwg % 8 == 0 for all launches here)
  const int nwg = nBx * nBy;
  int id = (int)blockIdx.x;
  id = (id & 7) * (nwg >> 3) + (id >> 3);
  const int bx = id % nBx;
  const int by = id / nBx;

  const int sel = bx / ntPerMat;
  const __hip_bfloat16* Bm = (sel == 0) ? B0 : ((sel == 1) ? B1 : B2);
  OutT* Cm = (sel == 0) ? C0 : ((sel == 1) ? C1 : C2);
  const int n0 = (bx - sel * ntPerMat) * 256;
  const int m0 = by * 256;

  // staging pointers: chunk c=j*512+t -> half-row c>>3, phys slot c&7,
  // global col pre-swizzled: (slot ^ (row&7))*8  (LDS dest linear)
  const int c0r = t >> 3, cs = t & 7;
  const int c1r = 64 + c0r;
  const __hip_bfloat16* aP0 = A + (size_t)(m0 + c0r) * K + (cs ^ (c0r & 7)) * 8;
  const __hip_bfloat16* aP1 = A + (size_t)(m0 + c1r) * K + (cs ^ (c1r & 7)) * 8;
  const __hip_bfloat16* bP0 = Bm + (size_t)(n0 + c0r) * K + (cs ^ (c0r & 7)) * 8;
  const __hip_bfloat16* bP1 = Bm + (size_t)(n0 + c1r) * K + (cs ^ (c1r & 7)) * 8;
  const size_t HK = (size_t)128 * K;  // half-tile row advance

#define STAGE_S(sidx, nb, koff)                                              \
  do {                                                                       \
    if ((sidx) == 0) {                                                       \
      GLDS16(aP0 + (koff), (char*)As[nb] + t * 16);                          \
      GLDS16(aP1 + (koff), (char*)As[nb] + 8192 + t * 16);                   \
    } else if ((sidx) == 1) {                                                \
      GLDS16(bP0 + (koff), (char*)Bs[nb] + t * 16);                          \
      GLDS16(bP1 + (koff), (char*)Bs[nb] + 8192 + t * 16);                   \
    } else if ((sidx) == 2) {                                                \
      GLDS16(aP0 + HK + (koff), (char*)As[nb] + 16384 + t * 16);             \
      GLDS16(aP1 + HK + (koff), (char*)As[nb] + 24576 + t * 16);             \
    } else {                                                                 \
      GLDS16(bP0 + HK + (koff), (char*)Bs[nb] + 16384 + t * 16);             \
      GLDS16(bP1 + HK + (koff), (char*)Bs[nb] + 24576 + t * 16);             \
    }                                                                        \
  } while (0)

  f32x4 acc[2][2][4][2] = {};  // [mh][nh][mi][ni]
  const int NT = K / 64;
  const int sw = lr & 7;  // frag row & 7 == lr & 7 for every fragment row

#define PHASE(mh, nh, sidx)                                                  \
  do {                                                                       \
    asm volatile("s_waitcnt vmcnt(4)" ::: "memory");                         \
    __builtin_amdgcn_s_barrier();                                            \
    const char* as_ = (const char*)As[buf];                                  \
    const char* bs_ = (const char*)Bs[buf];                                  \
    bf16x8 af[4][2], bq[2][2];                                               \
    _Pragma("unroll") for (int mi = 0; mi < 4; ++mi)                         \
      _Pragma("unroll") for (int kk = 0; kk < 2; ++kk)                       \
        af[mi][kk] = *(const bf16x8*)(as_ +                                  \
            ((mh) * 128 + (w >> 2) * 64 + mi * 16 + lr) * 128 +              \
            (((kk * 4 + hi) ^ sw) << 4));                                    \
    _Pragma("unroll") for (int ni = 0; ni < 2; ++ni)                         \
      _Pragma("unroll") for (int kk = 0; kk < 2; ++kk)                       \
        bq[ni][kk] = *(const bf16x8*)(bs_ +                                  \
            ((nh) * 128 + (w & 3) * 32 + ni * 16 + lr) * 128 +               \
            (((kk * 4 + hi) ^ sw) << 4));                                    \
    if (tt + 1 < NT) STAGE_S((sidx), nb, (size_t)(tt + 1) * 64);             \
    __builtin_amdgcn_s_setprio(1);                                           \
    _Pragma("unroll") for (int mi = 0; mi < 4; ++mi)                         \
      _Pragma("unroll") for (int ni = 0; ni < 2; ++ni) {                     \
        acc[mh][nh][mi][ni] = __builtin_amdgcn_mfma_f32_16x16x32_bf16(       \
            af[mi][0], bq[ni][0], acc[mh][nh][mi][ni], 0, 0, 0);             \
        acc[mh][nh][mi][ni] = __builtin_amdgcn_mfma_f32_16x16x32_bf16(       \
            af[mi][1], bq[ni][1], acc[mh][nh][mi][ni], 0, 0, 0);             \
      }                                                                      \
    __builtin_amdgcn_s_setprio(0);                                           \
  } while (0)

  // prologue: tile 0's four halves into buf 0
  STAGE_S(0, 0, 0);
  STAGE_S(1, 0, 0);
  STAGE_S(2, 0, 0);
  STAGE_S(3, 0, 0);

  for (int tt = 0; tt < NT; ++tt) {
    const int buf = tt & 1, nb = buf ^ 1;
    PHASE(0, 0, 0);  // needs A0,B0 ; issues A0(t+1)
    PHASE(1, 0, 1);  // needs A1,B0 ; issues B0(t+1)
    PHASE(0, 1, 2);  // needs A0,B1 ; issues A1(t+1)
    PHASE(1, 1, 3);  // needs A1,B1 ; issues B1(t+1)
  }
#undef PHASE
#undef STAGE_S

  // C/D layout: col = lr, row = hi*4 + i
#pragma unroll
  for (int mh = 0; mh < 2; ++mh)
#pragma unroll
    for (int nh = 0; nh < 2; ++nh)
#pragma unroll
      for (int mi = 0; mi < 4; ++mi)
#pragma unroll
        for (int ni = 0; ni < 2; ++ni)
#pragma unroll
          for (int i = 0; i < 4; ++i) {
            size_t idx = (size_t)(m0 + mh * 128 + (w >> 2) * 64 + mi * 16 + hi * 4 + i) * N +
                         (n0 + nh * 128 + (w & 3) * 32 + ni * 16 + lr);
            store1(&Cm[idx], acc[mh][nh][mi][ni][i]);
          }
}

// ---------------- flash attention v4 (causal), swapped QK^T (unchanged) ----------------
__global__ __launch_bounds__(256, 2) void flash_attn(const __hip_bfloat16* __restrict__ Qg,
                                                     const __hip_bfloat16* __restrict__ Kg,
                                                     const __hip_bfloat16* __restrict__ Vg,
                                                     __hip_bfloat16* __restrict__ Og) {
  __shared__ __hip_bfloat16 Ks[2][64 * 128];  // [k][d], slot ^= (k&7) via source pre-swizzle
  __shared__ __hip_bfloat16 Vt[128 * 64];     // [d][k], slot ^= ((d>>3)^d)&7

  const int mblk = blockIdx.x;
  const int bh = mblk & 31;
  const int jj = mblk >> 5;                        // heavy q-tiles dispatch first
  const int qt = (jj < 8) ? (15 - jj) : (jj - 8);  // pair (c, c+256) sums to 34 tiles
  const int b = bh >> 4, h = bh & 15;
  const int q0 = qt * 128;
  const int t = threadIdx.x, w = t >> 6, l = t & 63;
  const int lr = l & 15, hi = l >> 4;
  const size_t base = ((size_t)b * 2048) * 2048 + (size_t)h * 128;
  const int nt = 2 * qt + 2;
  const float scale = 0.08838834764831843f;  // 1/sqrt(128)

  const int hi2 = (hi & 1) * 2;
  const int addrA = (((hi2) << 4) | lr) << 2;
  const int addrB = (((hi2 + 1) << 4) | lr) << 2;
  int addr_o[4];
#pragma unroll
  for (int i = 0; i < 4; ++i) addr_o[i] = ((l & 48) | (hi * 4 + i)) << 2;
  const bool hiHigh = (hi >> 1) != 0;

  bf16x8 qf[2][4];
#pragma unroll
  for (int g = 0; g < 2; ++g) {
    const __hip_bfloat16* qrow = Qg + base + (size_t)(q0 + w * 32 + g * 16 + lr) * 2048;
#pragma unroll
    for (int kk = 0; kk < 4; ++kk)
      qf[g][kk] = *(const bf16x8*)(qrow + kk * 32 + hi * 8);
  }

  f32x4 o_acc[2][8] = {};
  float m_run[2] = {-1e30f, -1e30f};
  float l_run[2] = {0.f, 0.f};

  const __hip_bfloat16* kptr[4];
#pragma unroll
  for (int i = 0; i < 4; ++i) {
    int c = i * 256 + t;
    int kr = c >> 4;
    int ke = ((c & 15) ^ (kr & 7)) * 8;
    kptr[i] = Kg + base + (size_t)kr * 2048 + ke;
  }
  const __hip_bfloat16* vptr[2];
#pragma unroll
  for (int it = 0; it < 2; ++it) {
    int kp = it * 16 + w * 4 + hi;
    vptr[it] = Vg + base + (size_t)(kp * 2) * 2048 + lr * 8;
  }

  u16x8 va[2], vb[2];
#pragma unroll
  for (int i = 0; i < 4; ++i)
    GLDS16(kptr[i], (char*)Ks[0] + (i * 256 + t) * 16);
#pragma unroll
  for (int it = 0; it < 2; ++it) {
    va[it] = *(const u16x8*)vptr[it];
    vb[it] = *(const u16x8*)(vptr[it] + 2048);
  }

  for (int kt = 0; kt < nt; ++kt) {
    const int cur = kt & 1;
    const int kb = kt * 64;
    __syncthreads();

#pragma unroll
    for (int it = 0; it < 2; ++it)
#pragma unroll
      for (int j2 = 0; j2 < 8; ++j2) {
        int d = lr * 8 + j2;
        int sw = (lr ^ j2) & 7;
        int off = d * 128 + (((it * 4 + w) ^ sw) << 4) + hi * 4;
        *(unsigned int*)((char*)Vt + off) =
            (unsigned int)va[it][j2] | ((unsigned int)vb[it][j2] << 16);
      }
    if (kt + 1 < nt) {
      const size_t adv = (size_t)(kb + 64) * 2048;
#pragma unroll
      for (int i = 0; i < 4; ++i)
        GLDS16(kptr[i] + adv, (char*)Ks[cur ^ 1] + (i * 256 + t) * 16);
#pragma unroll
      for (int it = 0; it < 2; ++it) {
        va[it] = *(const u16x8*)(vptr[it] + adv);
        vb[it] = *(const u16x8*)(vptr[it] + adv + 2048);
      }
    }
    asm volatile("s_waitcnt lgkmcnt(0)" ::: "memory");
    __builtin_amdgcn_s_barrier();

    if (!(kt == nt - 1 && w < 2)) {
      const char* ks = (const char*)Ks[cur];

      f32x4 st[2][4];
#pragma unroll
      for (int g = 0; g < 2; ++g)
#pragma unroll
        for (int nk = 0; nk < 4; ++nk) { f32x4 z = {}; st[g][nk] = z; }
#pragma unroll
      for (int nk = 0; nk < 4; ++nk)
#pragma unroll
        for (int kk = 0; kk < 4; ++kk) {
          bf16x8 kf = *(const bf16x8*)(ks + (nk * 16 + lr) * 256 +
                                       (((kk * 4 + hi) ^ (lr & 7)) << 4));
#pragma unroll
          for (int g = 0; g < 2; ++g)
            st[g][nk] = __builtin_amdgcn_mfma_f32_16x16x32_bf16(kf, qf[g][kk], st[g][nk], 0, 0, 0);
        }

      const bool maskt = (kt >= nt - 2);
#pragma unroll
      for (int g = 0; g < 2; ++g)
#pragma unroll
        for (int nk = 0; nk < 4; ++nk)
#pragma unroll
          for (int i = 0; i < 4; ++i) {
            float v = st[g][nk][i] * scale;
            if (maskt) {
              int ki = kb + nk * 16 + hi * 4 + i;
              int qi = q0 + w * 32 + g * 16 + lr;
              if (ki > qi) v = -1e30f;
            }
            st[g][nk][i] = v;
          }

      bf16x8 paf[2][2];
#pragma unroll
      for (int g = 0; g < 2; ++g) {
        float t0 = fmaxf(fmaxf(st[g][0][0], st[g][0][1]), fmaxf(st[g][0][2], st[g][0][3]));
        float t1 = fmaxf(fmaxf(st[g][1][0], st[g][1][1]), fmaxf(st[g][1][2], st[g][1][3]));
        float t2 = fmaxf(fmaxf(st[g][2][0], st[g][2][1]), fmaxf(st[g][2][2], st[g][2][3]));
        float t3 = fmaxf(fmaxf(st[g][3][0], st[g][3][1]), fmaxf(st[g][3][2], st[g][3][3]));
        float mx = fmaxf(fmaxf(t0, t1), fmaxf(t2, t3));
        mx = fmaxf(mx, __shfl_xor(mx, 16));
        mx = fmaxf(mx, __shfl_xor(mx, 32));

        if (!__all(mx - m_run[g] <= 8.0f)) {
          float mnew = fmaxf(m_run[g], mx);
          float rs = __expf(m_run[g] - mnew);
          m_run[g] = mnew;
          l_run[g] *= rs;
          int rsi = __float_as_int(rs);
#pragma unroll
          for (int i = 0; i < 4; ++i) {
            float rso = __int_as_float(__builtin_amdgcn_ds_bpermute(addr_o[i], rsi));
#pragma unroll
            for (int nc = 0; nc < 8; ++nc) o_acc[g][nc][i] *= rso;
          }
        }

#pragma unroll
        for (int nk = 0; nk < 4; ++nk)
#pragma unroll
          for (int i = 0; i < 4; ++i)
            st[g][nk][i] = __expf(st[g][nk][i] - m_run[g]);

        float s0 = (st[g][0][0] + st[g][0][1]) + (st[g][0][2] + st[g][0][3]);
        float s1 = (st[g][1][0] + st[g][1][1]) + (st[g][1][2] + st[g][1][3]);
        float s2 = (st[g][2][0] + st[g][2][1]) + (st[g][2][2] + st[g][2][3]);
        float s3 = (st[g][3][0] + st[g][3][1]) + (st[g][3][2] + st[g][3][3]);
        float sm = (s0 + s1) + (s2 + s3);
        sm += __shfl_xor(sm, 16);
        sm += __shfl_xor(sm, 32);
        l_run[g] += sm;

        unsigned pk[4][2];
#pragma unroll
        for (int nk = 0; nk < 4; ++nk) {
          asm("v_cvt_pk_bf16_f32 %0, %1, %2"
              : "=v"(pk[nk][0]) : "v"(st[g][nk][0]), "v"(st[g][nk][1]));
          asm("v_cvt_pk_bf16_f32 %0, %1, %2"
              : "=v"(pk[nk][1]) : "v"(st[g][nk][2]), "v"(st[g][nk][3]));
        }

#pragma unroll
        for (int kk = 0; kk < 2; ++kk) {
          unsigned au[4];
#pragma unroll
          for (int p = 0; p < 4; ++p) {
            int ad = (p < 2) ? addrA : addrB;
            int v0 = __builtin_amdgcn_ds_bpermute(ad, (int)pk[2 * kk][p & 1]);
            int v1 = __builtin_amdgcn_ds_bpermute(ad, (int)pk[2 * kk + 1][p & 1]);
            au[p] = hiHigh ? (unsigned)v1 : (unsigned)v0;
          }
          union { unsigned u[4]; bf16x8 v; } cv;
          cv.u[0] = au[0]; cv.u[1] = au[1]; cv.u[2] = au[2]; cv.u[3] = au[3];
          paf[g][kk] = cv.v;
        }
      }

#pragma unroll
      for (int kk = 0; kk < 2; ++kk)
#pragma unroll
        for (int nc = 0; nc < 8; ++nc) {
          int d = nc * 16 + lr;
          int sw = ((d >> 3) ^ d) & 7;
          bf16x8 vfr = *(const bf16x8*)((const char*)Vt + d * 128 +
                                        (((kk * 4 + hi) ^ sw) << 4));
#pragma unroll
          for (int g = 0; g < 2; ++g)
            o_acc[g][nc] = __builtin_amdgcn_mfma_f32_16x16x32_bf16(paf[g][kk], vfr, o_acc[g][nc], 0, 0, 0);
        }
    }
  }

#pragma unroll
  for (int g = 0; g < 2; ++g) {
    float lo[4];
#pragma unroll
    for (int i = 0; i < 4; ++i)
      lo[i] = __int_as_float(__builtin_amdgcn_ds_bpermute(addr_o[i], __float_as_int(l_run[g])));
#pragma unroll
    for (int nc = 0; nc < 8; ++nc)
#pragma unroll
      for (int i = 0; i < 4; ++i) {
        float val = o_acc[g][nc][i] / lo[i];
        Og[base + (size_t)(q0 + w * 32 + g * 16 + hi * 4 + i) * 2048 + nc * 16 + lr] =
            __float2bfloat16(val);
      }
  }
}

// ---------------- launch ----------------
extern "C" void kernel_launch(void* const* d_in, const int* in_sizes, int n_in,
                              void* d_out, int out_size, void* d_ws, size_t ws_size,
                              hipStream_t stream) {
  const float* x  = (const float*)d_in[0];
  const float* wq = (const float*)d_in[1];
  const float* wk = (const float*)d_in[2];
  const float* wv = (const float*)d_in[3];
  const float* wo = (const float*)d_in[4];
  float* out = (float*)d_out;

  const int BT = 4096, D = 2048;
  const size_t ND = (size_t)D * D;
  const size_t NX = (size_t)BT * D;

  __hip_bfloat16* xb  = (__hip_bfloat16*)d_ws;
  __hip_bfloat16* wqb = xb + NX;
  __hip_bfloat16* wkb = wqb + ND;
  __hip_bfloat16* wvb = wkb + ND;
  __hip_bfloat16* wob = wvb + ND;
  __hip_bfloat16* Qb  = wob + ND;
  __hip_bfloat16* Kb  = Qb + NX;
  __hip_bfloat16* Vb  = Kb + NX;
  __hip_bfloat16* Ab  = Vb + NX;

  cast_f32_to_bf16<<<(int)(NX / 4 / 256), 256, 0, stream>>>((const float4*)x,  (ushort4*)xb,  (int)(NX / 4));
  cast_f32_to_bf16<<<(int)(ND / 4 / 256), 256, 0, stream>>>((const float4*)wq, (ushort4*)wqb, (int)(ND / 4));
  cast_f32_to_bf16<<<(int)(ND / 4 / 256), 256, 0, stream>>>((const float4*)wk, (ushort4*)wkb, (int)(ND / 4));
  cast_f32_to_bf16<<<(int)(ND / 4 / 256), 256, 0, stream>>>((const float4*)wv, (ushort4*)wvb, (int)(ND / 4));
  cast_f32_to_bf16<<<(int)(ND / 4 / 256), 256, 0, stream>>>((const float4*)wo, (ushort4*)wob, (int)(ND / 4));

  // fused QKV: 16 M-tiles x 24 N-tiles (8 per matrix) = 384 blocks
  gemm256<__hip_bfloat16><<<384, 512, 0, stream>>>(xb, wqb, wkb, wvb, Qb, Kb, Vb,
                                                   24, 16, 8, D, D);

  flash_attn<<<512, 256, 0, stream>>>(Qb, Kb, Vb, Ab);

  // output projection: 8 x 16 = 128 blocks
  gemm256<float><<<128, 512, 0, stream>>>(Ab, wob, wob, wob, out, out, out,
                                          8, 16, 8, D, D);
}

// Round 7
// 291.810 us; speedup vs baseline: 1.9379x; 1.0350x over previous
//
#include <hip/hip_runtime.h>
#include <hip/hip_bf16.h>

typedef __bf16 bf16x8 __attribute__((ext_vector_type(8)));
typedef float f32x4 __attribute__((ext_vector_type(4)));
typedef unsigned short u16x8 __attribute__((ext_vector_type(8)));

#define GLDS16(g, s)                                                         \
  __builtin_amdgcn_global_load_lds(                                          \
      (const __attribute__((address_space(1))) void*)(g),                    \
      (__attribute__((address_space(3))) void*)(s), 16, 0, 0)

__device__ __forceinline__ void store1(__hip_bfloat16* p, float v) { *p = __float2bfloat16(v); }
__device__ __forceinline__ void store1(float* p, float v) { *p = v; }

// ---------------- cast fp32 -> bf16 ----------------
__global__ __launch_bounds__(256) void cast_f32_to_bf16(const float4* __restrict__ in,
                                                        ushort4* __restrict__ out, int n4) {
  int i = blockIdx.x * 256 + threadIdx.x;
  if (i >= n4) return;
  float4 v = in[i];
  union { ushort4 u; __hip_bfloat16 h[4]; } o;
  o.h[0] = __float2bfloat16(v.x);
  o.h[1] = __float2bfloat16(v.y);
  o.h[2] = __float2bfloat16(v.z);
  o.h[3] = __float2bfloat16(v.w);
  out[i] = o.u;
}

// ---------------- 8-phase 256x256 bf16 GEMM: C(MxN) = A(MxK) * B(NxK)^T --------------
// BK=64, 512 threads = 8 waves. Serpentine phase order (0,0)->(0,1)->(1,1)->(1,0)
// with persistent fragments: af re-read only on mh change, both B quadrants held
// all tile -> 24 ds_read_b128 / wave / K-tile (Ph4 = pure MFMA).
// Staging halves: issue order A0',B0',B1',A1' at Ph1..Ph4 into buf^1.
// Per phase: vmcnt(4) (2 newest halves may be in flight) + raw s_barrier.
// Proof (steady state, issue trace ...B1(t),A1(t),A0(t+1),B0(t+1),B1(t+1),A1(t+1)...):
//  Ph1(t) needs A0,B0(t): not-landed <= {B1(t),A1(t)} ok
//  Ph2(t) needs B1(t):    not-landed <= {A1(t),A0(t+1)} ok
//  Ph3(t) needs A1(t):    not-landed <= {A0(t+1),B0(t+1)} ok
//  Ph4(t) reads nothing new. Tail tile: vmcnt(0) at every phase (drain race fix).
template <typename OutT>
__global__ __launch_bounds__(512, 2) void gemm256(const __hip_bfloat16* __restrict__ A,
                                                  const __hip_bfloat16* __restrict__ B0,
                                                  const __hip_bfloat16* __restrict__ B1,
                                                  const __hip_bfloat16* __restrict__ B2,
                                                  OutT* __restrict__ C0,
                                                  OutT* __restrict__ C1,
                                                  OutT* __restrict__ C2,
                                                  int nBx, int nBy, int ntPerMat,
                                                  int N, int K) {
  __shared__ __hip_bfloat16 As[2][256 * 64];  // 32 KB per buf
  __shared__ __hip_bfloat16 Bs[2][256 * 64];  // 32 KB per buf

  const int t = threadIdx.x;
  const int w = t >> 6, l = t & 63;
  const int lr = l & 15, hi = l >> 4;

  // XCD-bijective swizzle (nwg % 8 == 0 for all launches here)
  const int nwg = nBx * nBy;
  int id = (int)blockIdx.x;
  id = (id & 7) * (nwg >> 3) + (id >> 3);
  // A-major decode: consecutive ids share bx (weight N-panel stays L2-resident)
  const int bx = id / nBy;
  const int by = id % nBy;

  const int sel = bx / ntPerMat;
  const __hip_bfloat16* Bm = (sel == 0) ? B0 : ((sel == 1) ? B1 : B2);
  OutT* Cm = (sel == 0) ? C0 : ((sel == 1) ? C1 : C2);
  const int n0 = (bx - sel * ntPerMat) * 256;
  const int m0 = by * 256;

  // staging: chunk c -> half-row c>>3, phys slot c&7; global col pre-swizzled
  const int c0r = t >> 3, cs = t & 7;
  const int c1r = 64 + c0r;
  const __hip_bfloat16* aP0 = A + (size_t)(m0 + c0r) * K + (cs ^ (c0r & 7)) * 8;
  const __hip_bfloat16* aP1 = A + (size_t)(m0 + c1r) * K + (cs ^ (c1r & 7)) * 8;
  const __hip_bfloat16* bP0 = Bm + (size_t)(n0 + c0r) * K + (cs ^ (c0r & 7)) * 8;
  const __hip_bfloat16* bP1 = Bm + (size_t)(n0 + c1r) * K + (cs ^ (c1r & 7)) * 8;
  const size_t HK = (size_t)128 * K;  // half-tile row advance

  // sidx: 0=A0, 1=B0, 2=A1, 3=B1
#define STAGE_S(sidx, nb, koff)                                              \
  do {                                                                       \
    if ((sidx) == 0) {                                                       \
      GLDS16(aP0 + (koff), (char*)As[nb] + t * 16);                          \
      GLDS16(aP1 + (koff), (char*)As[nb] + 8192 + t * 16);                   \
    } else if ((sidx) == 1) {                                                \
      GLDS16(bP0 + (koff), (char*)Bs[nb] + t * 16);                          \
      GLDS16(bP1 + (koff), (char*)Bs[nb] + 8192 + t * 16);                   \
    } else if ((sidx) == 2) {                                                \
      GLDS16(aP0 + HK + (koff), (char*)As[nb] + 16384 + t * 16);             \
      GLDS16(aP1 + HK + (koff), (char*)As[nb] + 24576 + t * 16);             \
    } else {                                                                 \
      GLDS16(bP0 + HK + (koff), (char*)Bs[nb] + 16384 + t * 16);             \
      GLDS16(bP1 + HK + (koff), (char*)Bs[nb] + 24576 + t * 16);             \
    }                                                                        \
  } while (0)

  f32x4 acc[2][2][4][2] = {};  // [mh][nh][mi][ni]
  bf16x8 af[4][2];             // A frags, current mh
  bf16x8 bqA[2][2], bqB[2][2]; // B frags, nh=0 / nh=1 (held whole tile)
  const int NT = K / 64;
  const int sw = lr & 7;
  const int arow = (w >> 2) * 64;  // + mh*128
  const int brow = (w & 3) * 32;   // + nh*128

#define LOAD_A(mh)                                                           \
  _Pragma("unroll") for (int mi = 0; mi < 4; ++mi)                           \
    _Pragma("unroll") for (int kk = 0; kk < 2; ++kk)                         \
      af[mi][kk] = *(const bf16x8*)((const char*)As[buf] +                   \
          ((mh) * 128 + arow + mi * 16 + lr) * 128 + (((kk * 4 + hi) ^ sw) << 4));
#define LOAD_B(dst, nh)                                                      \
  _Pragma("unroll") for (int ni = 0; ni < 2; ++ni)                           \
    _Pragma("unroll") for (int kk = 0; kk < 2; ++kk)                         \
      dst[ni][kk] = *(const bf16x8*)((const char*)Bs[buf] +                  \
          ((nh) * 128 + brow + ni * 16 + lr) * 128 + (((kk * 4 + hi) ^ sw) << 4));
#define MFMA_Q(mh, nh, bq)                                                   \
  do {                                                                       \
    __builtin_amdgcn_s_setprio(1);                                           \
    _Pragma("unroll") for (int mi = 0; mi < 4; ++mi)                         \
      _Pragma("unroll") for (int ni = 0; ni < 2; ++ni) {                     \
        acc[mh][nh][mi][ni] = __builtin_amdgcn_mfma_f32_16x16x32_bf16(       \
            af[mi][0], bq[ni][0], acc[mh][nh][mi][ni], 0, 0, 0);             \
        acc[mh][nh][mi][ni] = __builtin_amdgcn_mfma_f32_16x16x32_bf16(       \
            af[mi][1], bq[ni][1], acc[mh][nh][mi][ni], 0, 0, 0);             \
      }                                                                      \
    __builtin_amdgcn_s_setprio(0);                                           \
  } while (0)
#define WAITB(lastt)                                                         \
  do {                                                                       \
    if (lastt) asm volatile("s_waitcnt vmcnt(0)" ::: "memory");              \
    else       asm volatile("s_waitcnt vmcnt(4)" ::: "memory");              \
    __builtin_amdgcn_s_barrier();                                            \
  } while (0)

  // prologue: tile 0 halves in issue order A0,B0,B1,A1
  STAGE_S(0, 0, 0);
  STAGE_S(1, 0, 0);
  STAGE_S(3, 0, 0);
  STAGE_S(2, 0, 0);

  for (int tt = 0; tt < NT; ++tt) {
    const int buf = tt & 1, nb = buf ^ 1;
    const bool stg = (tt + 1 < NT);
    const bool lastt = !stg;
    const size_t ko = (size_t)(tt + 1) * 64;

    WAITB(lastt);                       // Ph1 (0,0)
    LOAD_A(0); LOAD_B(bqA, 0);
    if (stg) STAGE_S(0, nb, ko);        // issue A0'
    MFMA_Q(0, 0, bqA);

    WAITB(lastt);                       // Ph2 (0,1)
    LOAD_B(bqB, 1);
    if (stg) STAGE_S(1, nb, ko);        // issue B0'
    MFMA_Q(0, 1, bqB);

    WAITB(lastt);                       // Ph3 (1,1)
    LOAD_A(1);
    if (stg) STAGE_S(3, nb, ko);        // issue B1'
    MFMA_Q(1, 1, bqB);

    WAITB(lastt);                       // Ph4 (1,0) — pure MFMA
    if (stg) STAGE_S(2, nb, ko);        // issue A1'
    MFMA_Q(1, 0, bqA);
  }
#undef WAITB
#undef MFMA_Q
#undef LOAD_B
#undef LOAD_A
#undef STAGE_S

  // C/D layout: col = lr, row = hi*4 + i
#pragma unroll
  for (int mh = 0; mh < 2; ++mh)
#pragma unroll
    for (int nh = 0; nh < 2; ++nh)
#pragma unroll
      for (int mi = 0; mi < 4; ++mi)
#pragma unroll
        for (int ni = 0; ni < 2; ++ni)
#pragma unroll
          for (int i = 0; i < 4; ++i) {
            size_t idx = (size_t)(m0 + mh * 128 + arow + mi * 16 + hi * 4 + i) * N +
                         (n0 + nh * 128 + brow + ni * 16 + lr);
            store1(&Cm[idx], acc[mh][nh][mi][ni][i]);
          }
}

// ---------------- flash attention v4 (causal), swapped QK^T (unchanged) ----------------
__global__ __launch_bounds__(256, 2) void flash_attn(const __hip_bfloat16* __restrict__ Qg,
                                                     const __hip_bfloat16* __restrict__ Kg,
                                                     const __hip_bfloat16* __restrict__ Vg,
                                                     __hip_bfloat16* __restrict__ Og) {
  __shared__ __hip_bfloat16 Ks[2][64 * 128];  // [k][d], slot ^= (k&7) via source pre-swizzle
  __shared__ __hip_bfloat16 Vt[128 * 64];     // [d][k], slot ^= ((d>>3)^d)&7

  const int mblk = blockIdx.x;
  const int bh = mblk & 31;
  const int jj = mblk >> 5;                        // heavy q-tiles dispatch first
  const int qt = (jj < 8) ? (15 - jj) : (jj - 8);  // pair (c, c+256) sums to 34 tiles
  const int b = bh >> 4, h = bh & 15;
  const int q0 = qt * 128;
  const int t = threadIdx.x, w = t >> 6, l = t & 63;
  const int lr = l & 15, hi = l >> 4;
  const size_t base = ((size_t)b * 2048) * 2048 + (size_t)h * 128;
  const int nt = 2 * qt + 2;
  const float scale = 0.08838834764831843f;  // 1/sqrt(128)

  const int hi2 = (hi & 1) * 2;
  const int addrA = (((hi2) << 4) | lr) << 2;
  const int addrB = (((hi2 + 1) << 4) | lr) << 2;
  int addr_o[4];
#pragma unroll
  for (int i = 0; i < 4; ++i) addr_o[i] = ((l & 48) | (hi * 4 + i)) << 2;
  const bool hiHigh = (hi >> 1) != 0;

  bf16x8 qf[2][4];
#pragma unroll
  for (int g = 0; g < 2; ++g) {
    const __hip_bfloat16* qrow = Qg + base + (size_t)(q0 + w * 32 + g * 16 + lr) * 2048;
#pragma unroll
    for (int kk = 0; kk < 4; ++kk)
      qf[g][kk] = *(const bf16x8*)(qrow + kk * 32 + hi * 8);
  }

  f32x4 o_acc[2][8] = {};
  float m_run[2] = {-1e30f, -1e30f};
  float l_run[2] = {0.f, 0.f};

  const __hip_bfloat16* kptr[4];
#pragma unroll
  for (int i = 0; i < 4; ++i) {
    int c = i * 256 + t;
    int kr = c >> 4;
    int ke = ((c & 15) ^ (kr & 7)) * 8;
    kptr[i] = Kg + base + (size_t)kr * 2048 + ke;
  }
  const __hip_bfloat16* vptr[2];
#pragma unroll
  for (int it = 0; it < 2; ++it) {
    int kp = it * 16 + w * 4 + hi;
    vptr[it] = Vg + base + (size_t)(kp * 2) * 2048 + lr * 8;
  }

  u16x8 va[2], vb[2];
#pragma unroll
  for (int i = 0; i < 4; ++i)
    GLDS16(kptr[i], (char*)Ks[0] + (i * 256 + t) * 16);
#pragma unroll
  for (int it = 0; it < 2; ++it) {
    va[it] = *(const u16x8*)vptr[it];
    vb[it] = *(const u16x8*)(vptr[it] + 2048);
  }

  for (int kt = 0; kt < nt; ++kt) {
    const int cur = kt & 1;
    const int kb = kt * 64;
    __syncthreads();

#pragma unroll
    for (int it = 0; it < 2; ++it)
#pragma unroll
      for (int j2 = 0; j2 < 8; ++j2) {
        int d = lr * 8 + j2;
        int sw = (lr ^ j2) & 7;
        int off = d * 128 + (((it * 4 + w) ^ sw) << 4) + hi * 4;
        *(unsigned int*)((char*)Vt + off) =
            (unsigned int)va[it][j2] | ((unsigned int)vb[it][j2] << 16);
      }
    if (kt + 1 < nt) {
      const size_t adv = (size_t)(kb + 64) * 2048;
#pragma unroll
      for (int i = 0; i < 4; ++i)
        GLDS16(kptr[i] + adv, (char*)Ks[cur ^ 1] + (i * 256 + t) * 16);
#pragma unroll
      for (int it = 0; it < 2; ++it) {
        va[it] = *(const u16x8*)(vptr[it] + adv);
        vb[it] = *(const u16x8*)(vptr[it] + adv + 2048);
      }
    }
    asm volatile("s_waitcnt lgkmcnt(0)" ::: "memory");
    __builtin_amdgcn_s_barrier();

    if (!(kt == nt - 1 && w < 2)) {
      const char* ks = (const char*)Ks[cur];

      f32x4 st[2][4];
#pragma unroll
      for (int g = 0; g < 2; ++g)
#pragma unroll
        for (int nk = 0; nk < 4; ++nk) { f32x4 z = {}; st[g][nk] = z; }
#pragma unroll
      for (int nk = 0; nk < 4; ++nk)
#pragma unroll
        for (int kk = 0; kk < 4; ++kk) {
          bf16x8 kf = *(const bf16x8*)(ks + (nk * 16 + lr) * 256 +
                                       (((kk * 4 + hi) ^ (lr & 7)) << 4));
#pragma unroll
          for (int g = 0; g < 2; ++g)
            st[g][nk] = __builtin_amdgcn_mfma_f32_16x16x32_bf16(kf, qf[g][kk], st[g][nk], 0, 0, 0);
        }

      const bool maskt = (kt >= nt - 2);
#pragma unroll
      for (int g = 0; g < 2; ++g)
#pragma unroll
        for (int nk = 0; nk < 4; ++nk)
#pragma unroll
          for (int i = 0; i < 4; ++i) {
            float v = st[g][nk][i] * scale;
            if (maskt) {
              int ki = kb + nk * 16 + hi * 4 + i;
              int qi = q0 + w * 32 + g * 16 + lr;
              if (ki > qi) v = -1e30f;
            }
            st[g][nk][i] = v;
          }

      bf16x8 paf[2][2];
#pragma unroll
      for (int g = 0; g < 2; ++g) {
        float t0 = fmaxf(fmaxf(st[g][0][0], st[g][0][1]), fmaxf(st[g][0][2], st[g][0][3]));
        float t1 = fmaxf(fmaxf(st[g][1][0], st[g][1][1]), fmaxf(st[g][1][2], st[g][1][3]));
        float t2 = fmaxf(fmaxf(st[g][2][0], st[g][2][1]), fmaxf(st[g][2][2], st[g][2][3]));
        float t3 = fmaxf(fmaxf(st[g][3][0], st[g][3][1]), fmaxf(st[g][3][2], st[g][3][3]));
        float mx = fmaxf(fmaxf(t0, t1), fmaxf(t2, t3));
        mx = fmaxf(mx, __shfl_xor(mx, 16));
        mx = fmaxf(mx, __shfl_xor(mx, 32));

        if (!__all(mx - m_run[g] <= 8.0f)) {
          float mnew = fmaxf(m_run[g], mx);
          float rs = __expf(m_run[g] - mnew);
          m_run[g] = mnew;
          l_run[g] *= rs;
          int rsi = __float_as_int(rs);
#pragma unroll
          for (int i = 0; i < 4; ++i) {
            float rso = __int_as_float(__builtin_amdgcn_ds_bpermute(addr_o[i], rsi));
#pragma unroll
            for (int nc = 0; nc < 8; ++nc) o_acc[g][nc][i] *= rso;
          }
        }

#pragma unroll
        for (int nk = 0; nk < 4; ++nk)
#pragma unroll
          for (int i = 0; i < 4; ++i)
            st[g][nk][i] = __expf(st[g][nk][i] - m_run[g]);

        float s0 = (st[g][0][0] + st[g][0][1]) + (st[g][0][2] + st[g][0][3]);
        float s1 = (st[g][1][0] + st[g][1][1]) + (st[g][1][2] + st[g][1][3]);
        float s2 = (st[g][2][0] + st[g][2][1]) + (st[g][2][2] + st[g][2][3]);
        float s3 = (st[g][3][0] + st[g][3][1]) + (st[g][3][2] + st[g][3][3]);
        float sm = (s0 + s1) + (s2 + s3);
        sm += __shfl_xor(sm, 16);
        sm += __shfl_xor(sm, 32);
        l_run[g] += sm;

        unsigned pk[4][2];
#pragma unroll
        for (int nk = 0; nk < 4; ++nk) {
          asm("v_cvt_pk_bf16_f32 %0, %1, %2"
              : "=v"(pk[nk][0]) : "v"(st[g][nk][0]), "v"(st[g][nk][1]));
          asm("v_cvt_pk_bf16_f32 %0, %1, %2"
              : "=v"(pk[nk][1]) : "v"(st[g][nk][2]), "v"(st[g][nk][3]));
        }

#pragma unroll
        for (int kk = 0; kk < 2; ++kk) {
          unsigned au[4];
#pragma unroll
          for (int p = 0; p < 4; ++p) {
            int ad = (p < 2) ? addrA : addrB;
            int v0 = __builtin_amdgcn_ds_bpermute(ad, (int)pk[2 * kk][p & 1]);
            int v1 = __builtin_amdgcn_ds_bpermute(ad, (int)pk[2 * kk + 1][p & 1]);
            au[p] = hiHigh ? (unsigned)v1 : (unsigned)v0;
          }
          union { unsigned u[4]; bf16x8 v; } cv;
          cv.u[0] = au[0]; cv.u[1] = au[1]; cv.u[2] = au[2]; cv.u[3] = au[3];
          paf[g][kk] = cv.v;
        }
      }

#pragma unroll
      for (int kk = 0; kk < 2; ++kk)
#pragma unroll
        for (int nc = 0; nc < 8; ++nc) {
          int d = nc * 16 + lr;
          int sw = ((d >> 3) ^ d) & 7;
          bf16x8 vfr = *(const bf16x8*)((const char*)Vt + d * 128 +
                                        (((kk * 4 + hi) ^ sw) << 4));
#pragma unroll
          for (int g = 0; g < 2; ++g)
            o_acc[g][nc] = __builtin_amdgcn_mfma_f32_16x16x32_bf16(paf[g][kk], vfr, o_acc[g][nc], 0, 0, 0);
        }
    }
  }

#pragma unroll
  for (int g = 0; g < 2; ++g) {
    float lo[4];
#pragma unroll
    for (int i = 0; i < 4; ++i)
      lo[i] = __int_as_float(__builtin_amdgcn_ds_bpermute(addr_o[i], __float_as_int(l_run[g])));
#pragma unroll
    for (int nc = 0; nc < 8; ++nc)
#pragma unroll
      for (int i = 0; i < 4; ++i) {
        float val = o_acc[g][nc][i] / lo[i];
        Og[base + (size_t)(q0 + w * 32 + g * 16 + hi * 4 + i) * 2048 + nc * 16 + lr] =
            __float2bfloat16(val);
      }
  }
}

// ---------------- launch ----------------
extern "C" void kernel_launch(void* const* d_in, const int* in_sizes, int n_in,
                              void* d_out, int out_size, void* d_ws, size_t ws_size,
                              hipStream_t stream) {
  const float* x  = (const float*)d_in[0];
  const float* wq = (const float*)d_in[1];
  const float* wk = (const float*)d_in[2];
  const float* wv = (const float*)d_in[3];
  const float* wo = (const float*)d_in[4];
  float* out = (float*)d_out;

  const int BT = 4096, D = 2048;
  const size_t ND = (size_t)D * D;
  const size_t NX = (size_t)BT * D;

  __hip_bfloat16* xb  = (__hip_bfloat16*)d_ws;
  __hip_bfloat16* wqb = xb + NX;
  __hip_bfloat16* wkb = wqb + ND;
  __hip_bfloat16* wvb = wkb + ND;
  __hip_bfloat16* wob = wvb + ND;
  __hip_bfloat16* Qb  = wob + ND;
  __hip_bfloat16* Kb  = Qb + NX;
  __hip_bfloat16* Vb  = Kb + NX;
  __hip_bfloat16* Ab  = Vb + NX;

  cast_f32_to_bf16<<<(int)(NX / 4 / 256), 256, 0, stream>>>((const float4*)x,  (ushort4*)xb,  (int)(NX / 4));
  cast_f32_to_bf16<<<(int)(ND / 4 / 256), 256, 0, stream>>>((const float4*)wq, (ushort4*)wqb, (int)(ND / 4));
  cast_f32_to_bf16<<<(int)(ND / 4 / 256), 256, 0, stream>>>((const float4*)wk, (ushort4*)wkb, (int)(ND / 4));
  cast_f32_to_bf16<<<(int)(ND / 4 / 256), 256, 0, stream>>>((const float4*)wv, (ushort4*)wvb, (int)(ND / 4));
  cast_f32_to_bf16<<<(int)(ND / 4 / 256), 256, 0, stream>>>((const float4*)wo, (ushort4*)wob, (int)(ND / 4));

  // fused QKV: 16 M-tiles x 24 N-tiles (8 per matrix) = 384 blocks
  gemm256<__hip_bfloat16><<<384, 512, 0, stream>>>(xb, wqb, wkb, wvb, Qb, Kb, Vb,
                                                   24, 16, 8, D, D);

  flash_attn<<<512, 256, 0, stream>>>(Qb, Kb, Vb, Ab);

  // output projection: 8 x 16 = 128 blocks
  gemm256<float><<<128, 512, 0, stream>>>(Ab, wob, wob, wob, out, out, out,
                                          8, 16, 8, D, D);
}